// Round 16
// baseline (372.438 us; speedup 1.0000x reference)
//
#include <hip/hip_runtime.h>
#include <cstdint>
#include <cstddef>

#define Nn    4096
#define Ee    131072
#define INC   512
#define HIDC  512
#define HEADS 4
#define NLAY  3
#define GG    16
#define FW    2048   // HEADS*HIDC
#define ALDS  2112   // A LDS tile: 4 kq blocks x 66 rows x 8 shorts (bank-staggered)
#define BLDS  4160   // B LDS tile: 4 kq blocks x 130 rows x 8 shorts

typedef __attribute__((ext_vector_type(8))) short bfrag;   // 8 bf16 (4 VGPRs)
typedef __attribute__((ext_vector_type(4))) float ffrag;   // 4 fp32 acc

__device__ __forceinline__ ushort f2bf(float v){
  uint u = __builtin_bit_cast(uint, v);
  u += 0x7fffu + ((u>>16)&1u);          // RNE
  return (ushort)(u>>16);
}
__device__ __forceinline__ float bf2f(ushort s){
  uint u = ((uint)s)<<16; return __builtin_bit_cast(float, u);
}
// acc[0..7] += w * unpack8(bf16x8 in uint4)
__device__ __forceinline__ void fma8(float* acc, uint4 g, float w){
  uint u[4] = {g.x, g.y, g.z, g.w};
  #pragma unroll
  for (int q=0;q<4;q++){
    float lo = __builtin_bit_cast(float, u[q]<<16);
    float hi = __builtin_bit_cast(float, u[q] & 0xffff0000u);
    acc[2*q]   += w*lo;
    acc[2*q+1] += w*hi;
  }
}
__device__ __forceinline__ void pack8(void* p, const float* a){
  uint4 o;
  o.x = (uint)f2bf(a[0]) | ((uint)f2bf(a[1])<<16);
  o.y = (uint)f2bf(a[2]) | ((uint)f2bf(a[3])<<16);
  o.z = (uint)f2bf(a[4]) | ((uint)f2bf(a[5])<<16);
  o.w = (uint)f2bf(a[6]) | ((uint)f2bf(a[7])<<16);
  *(uint4*)p = o;
}
// pack 8 fp32 (two float4, memory order) -> 8 bf16 in uint4
__device__ __forceinline__ uint4 cvt8(float4 a, float4 b){
  uint4 o;
  o.x = (uint)f2bf(a.x) | ((uint)f2bf(a.y)<<16);
  o.y = (uint)f2bf(a.z) | ((uint)f2bf(a.w)<<16);
  o.z = (uint)f2bf(b.x) | ((uint)f2bf(b.y)<<16);
  o.w = (uint)f2bf(b.z) | ((uint)f2bf(b.w)<<16);
  return o;
}

// ---------------- fused prep: W transposes->bf16 | edge pass 1 ----------------
// blocks [0,1792): tbf (7 z-slices: 4 gat + 3 gcn); [1792,2304): edge_pass1
__global__ __launch_bounds__(256) void prep(
    const float* __restrict__ Wgat, ushort* __restrict__ Tgat,
    const float* __restrict__ Wgcn, ushort* __restrict__ Tgcn,
    const int* __restrict__ src, const int* __restrict__ dst,
    int* __restrict__ indeg, unsigned int* __restrict__ bitmap,
    int* __restrict__ cnt_s, int* __restrict__ flag){
  __shared__ float tile[32][33];
  int b = blockIdx.x, t = threadIdx.x;
  if (b < 1792){
    int z = b >> 8, xy = b & 255;
    const float* W; ushort* T; int bb;
    if (z < 4){ W = Wgat; T = Tgat; bb = z; } else { W = Wgcn; T = Tgcn; bb = z-4; }
    int r0 = (xy>>4)*32, c0 = (xy&15)*32;
    int i = t>>3, j0 = (t&7)*4;
    const float* Wb = W + (size_t)bb*512*512;
    float4 v = *(const float4*)(Wb + (size_t)(r0+i)*512 + c0 + j0);
    tile[i][j0]=v.x; tile[i][j0+1]=v.y; tile[i][j0+2]=v.z; tile[i][j0+3]=v.w;
    __syncthreads();
    ushort* o = T + (size_t)bb*512*512 + (size_t)(c0+i)*512 + r0 + j0;
    #pragma unroll
    for (int q=0;q<4;q++) o[q] = f2bf(tile[j0+q][i]);
  } else {
    int e = (b-1792)*256 + t; if (e>=Ee) return;
    int s = src[e], d = dst[e];
    atomicAdd(&indeg[d],1);
    unsigned int key = (unsigned int)s*Nn + (unsigned int)d;
    unsigned int bit = 1u<<(key&31);
    unsigned int old = atomicOr(&bitmap[key>>5], bit);
    int f = (old & bit) ? 0 : 1;
    flag[e] = f;
    if (f) atomicAdd(&cnt_s[s],1);
  }
}

// ---------------- bf16 MFMA GEMM core: C = A@B^T, 64(M)x128(N) tile, LDS double-buffer ----------------
// Bank-staggered LDS (kq stride A=66 rows, B=130 rows -> bank +8/kq on staging writes).
// AF32: A operand read as fp32, converted to bf16 in registers (same f2bf rounding).
// FUSELG: epilogue computes partial logits s1=v.a_src, s2=v.a_dst per row (LDS reduce + global atomics).
template<bool AF32, bool FUSELG>
__device__ __forceinline__ void gemm_core(
    const void* __restrict__ Av, const ushort* __restrict__ B,
    const ushort* Res, ushort* Cb,
    int N, int K, int relu_res, int m0, int n0,
    ushort* Ah, ushort* Bh,
    const float* a_src, const float* a_dst, float* lgs, float* lgd)
{
  __shared__ float lsum[64][2];
  int t = threadIdx.x;
  int srA = t>>2, kqA = t&3;
  int wA = (kqA*66 + srA)*8;
  int srB = t>>1, cB = t&1;
  const ushort* pB = B + (size_t)(n0+srB)*K + cB*16;
  int wB0 = ((2*cB)*130 + srB)*8;
  int wB1 = wB0 + 130*8;

  int wave = t>>6, lane = t&63;
  int wm = (wave&1)*32, wn = (wave>>1)*64;
  int lm = lane&15, quad = lane>>4;

  if (FUSELG){
    if (t < 128) lsum[t>>1][t&1] = 0.f;
  }

  ffrag acc[2][4];
  #pragma unroll
  for (int i=0;i<2;i++){
    #pragma unroll
    for (int j=0;j<4;j++) acc[i][j] = (ffrag){0.f,0.f,0.f,0.f};
  }

  const ushort* pA16 = (const ushort*)Av + (size_t)(m0+srA)*K + kqA*8;
  const float*  pA32 = (const float*)Av  + (size_t)(m0+srA)*K + kqA*8;

  uint4 ra; float4 raf0, raf1;
  if (AF32){ raf0 = *(const float4*)(pA32); raf1 = *(const float4*)(pA32+4); }
  else     { ra = *(const uint4*)(pA16); }
  uint4 rb0 = *(const uint4*)(pB);  uint4 rb1 = *(const uint4*)(pB+8);
  *(uint4*)&Ah[wA]  = AF32 ? cvt8(raf0, raf1) : ra;
  *(uint4*)&Bh[wB0] = rb0; *(uint4*)&Bh[wB1] = rb1;
  if (K > 32){
    if (AF32){ raf0 = *(const float4*)(pA32+32); raf1 = *(const float4*)(pA32+36); }
    else     { ra = *(const uint4*)(pA16+32); }
    rb0 = *(const uint4*)(pB+32); rb1 = *(const uint4*)(pB+40);
  }
  __syncthreads();

  for (int k0 = 0; k0 < K; k0 += 32){
    int cur = (k0>>5)&1, nxt = cur^1;
    const ushort* Ac = Ah + cur*ALDS;
    const ushort* Bc = Bh + cur*BLDS;
    bfrag af[2];
    #pragma unroll
    for (int mt=0; mt<2; mt++)
      af[mt] = *(const bfrag*)&Ac[(quad*66 + wm + mt*16 + lm)*8];
    #pragma unroll
    for (int nt=0; nt<4; nt++){
      bfrag bf = *(const bfrag*)&Bc[(quad*130 + wn + nt*16 + lm)*8];
      #pragma unroll
      for (int mt=0; mt<2; mt++)
        acc[mt][nt] = __builtin_amdgcn_mfma_f32_16x16x32_bf16(af[mt], bf, acc[mt][nt], 0,0,0);
    }
    if (k0+32 < K){
      *(uint4*)&Ah[nxt*ALDS + wA]  = AF32 ? cvt8(raf0, raf1) : ra;
      *(uint4*)&Bh[nxt*BLDS + wB0] = rb0; *(uint4*)&Bh[nxt*BLDS + wB1] = rb1;
      if (k0+64 < K){
        if (AF32){ raf0 = *(const float4*)(pA32+k0+64); raf1 = *(const float4*)(pA32+k0+68); }
        else     { ra = *(const uint4*)(pA16+k0+64); }
        rb0 = *(const uint4*)(pB+k0+64); rb1 = *(const uint4*)(pB+k0+72);
      }
    }
    __syncthreads();
  }

  float asv[4], adv[4];
  if (FUSELG){
    #pragma unroll
    for (int nt=0;nt<4;nt++){
      int gcol = n0 + wn + nt*16 + lm;   // a_src/a_dst are [HEADS][HIDC] flat = FW
      asv[nt] = a_src[gcol]; adv[nt] = a_dst[gcol];
    }
  }
  #pragma unroll
  for (int mt=0; mt<2; mt++){
    #pragma unroll
    for (int r=0;r<4;r++){
      int row = wm + mt*16 + quad*4 + r;
      int grow = m0 + row;
      float p1 = 0.f, p2 = 0.f;
      #pragma unroll
      for (int nt=0; nt<4; nt++){
        int gcol = n0 + wn + nt*16 + lm;
        size_t off = (size_t)grow*N + gcol;
        float v = acc[mt][nt][r];
        if (relu_res) v = fmaxf(v,0.f) + bf2f(Res[off]);
        Cb[off] = f2bf(v);
        if (FUSELG){ p1 += v*asv[nt]; p2 += v*adv[nt]; }
      }
      if (FUSELG){
        atomicAdd(&lsum[row][0], p1);
        atomicAdd(&lsum[row][1], p2);
      }
    }
  }
  if (FUSELG){
    __syncthreads();
    if (t < 64){
      int hd = n0 >> 9;
      atomicAdd(&lgs[(size_t)(m0+t)*HEADS + hd], lsum[t][0]);
      atomicAdd(&lgd[(size_t)(m0+t)*HEADS + hd], lsum[t][1]);
    }
  }
}

__global__ __launch_bounds__(256) void gemm_bf(
    const ushort* __restrict__ A, const ushort* __restrict__ B,
    const ushort* Res, ushort* Cb,
    int N, int K, int relu_res)
{
  __shared__ __align__(16) ushort Ah[2*ALDS];
  __shared__ __align__(16) ushort Bh[2*BLDS];
  gemm_core<false,false>(A, B, Res, Cb, N, K, relu_res,
                         blockIdx.y*64, blockIdx.x*128, Ah, Bh,
                         nullptr, nullptr, nullptr, nullptr);
}

// ---------------- fused: GAT projection gemm (fp32 A, fused logits) + edge scatter ----------------
__global__ __launch_bounds__(256) void gat_gemm_ep2(
    const float* __restrict__ x, const ushort* __restrict__ WgatT, ushort* __restrict__ hbf,
    const float* __restrict__ a_src, const float* __restrict__ a_dst,
    float* __restrict__ lgs, float* __restrict__ lgd,
    const int* __restrict__ src, const int* __restrict__ dst, const int* __restrict__ flag,
    const int* __restrict__ rp_d, int* __restrict__ fill_d, int* __restrict__ slist,
    const int* __restrict__ rp_s, int* __restrict__ fill_s, int2* __restrict__ cw,
    const float* __restrict__ dinv)
{
  __shared__ __align__(16) ushort Ah[2*ALDS];
  __shared__ __align__(16) ushort Bh[2*BLDS];
  int b = blockIdx.x;
  if (b < 1024){
    int m0 = (b>>4)*64, n0 = (b&15)*128;   // M=Nn (64 tiles), N=FW (16 tiles)
    gemm_core<true,true>(x, WgatT, nullptr, hbf, FW, INC, 0, m0, n0, Ah, Bh,
                         a_src, a_dst, lgs, lgd);
  } else {
    int e = (b-1024)*256 + threadIdx.x; if (e>=Ee) return;
    int s = src[e], d = dst[e];
    int p = atomicAdd(&fill_d[d],1); slist[rp_d[d]+p] = s;
    if (flag[e]){
      int q = atomicAdd(&fill_s[s],1);
      cw[rp_s[s]+q] = make_int2(d, __float_as_int(dinv[d]));
    }
  }
}

// ---------------- scan3: block0 scan indeg; block1 scan cnt_s + dinv; block2 goff ----------------
__global__ __launch_bounds__(1024) void scan3(const int* __restrict__ indeg, int* __restrict__ rp_d,
    const int* __restrict__ cnt_s, int* __restrict__ rp_s, float* __restrict__ dinv,
    const int* __restrict__ batch, int* __restrict__ goff){
  __shared__ int sums[1024];
  __shared__ int cnt2[GG];
  int t = threadIdx.x;
  if (blockIdx.x == 2){
    if (t<GG) cnt2[t]=0;
    __syncthreads();
    for (int i=t;i<Nn;i+=1024) atomicAdd(&cnt2[batch[i]],1);
    __syncthreads();
    if (t==0){ int run=0; for (int g=0; g<GG; g++){ goff[g]=run; run+=cnt2[g]; } goff[GG]=run; }
    return;
  }
  const int* cnt = blockIdx.x ? cnt_s : indeg;
  int* rowptr    = blockIdx.x ? rp_s  : rp_d;
  int v[4]; int s=0;
  #pragma unroll
  for (int i=0;i<4;i++){ int idx=t*4+i; v[i] = cnt[idx]; s+=v[i]; }
  sums[t]=s; __syncthreads();
  for (int off=1; off<1024; off<<=1){
    int other = (t>=off)? sums[t-off] : 0;
    __syncthreads();
    sums[t] += other;
    __syncthreads();
  }
  int run = (t>0)? sums[t-1] : 0;
  #pragma unroll
  for (int i=0;i<4;i++){
    int idx=t*4+i; rowptr[idx]=run; run+=v[i];
    if (blockIdx.x) dinv[idx] = 1.0f/sqrtf((float)(1+v[i]));
  }
  if (t==1023) rowptr[Nn]=sums[1023];
}

// ---------------- GAT softmax-aggregate: block = (4 nodes) x (1 head), wave = node ----------------
__global__ __launch_bounds__(256) void gat_aggregate(const ushort* __restrict__ hbf,
    const float* __restrict__ lgs, const float* __restrict__ lgd,
    const int* __restrict__ rowptr, const int* __restrict__ slist,
    ushort* __restrict__ Hbf){
  int t = threadIdx.x;
  int wv = __builtin_amdgcn_readfirstlane(t>>6);
  int lane = t&63;
  int b = blockIdx.x;
  int hd = __builtin_amdgcn_readfirstlane(b & 3);
  int n = ((b>>2)<<2) + wv;
  int beg = __builtin_amdgcn_readfirstlane(rowptr[n]);
  int end = __builtin_amdgcn_readfirstlane(rowptr[n+1]);
  int deg = end - beg;
  float ldst = lgd[n*HEADS+hd];
  // ---- single-pass online softmax (m,z), lane-parallel ----
  float m_ = -3.4e38f, z_ = 0.f;
  for (int i=lane; i<deg; i+=64){
    int s = slist[beg+i];
    float v = lgs[s*HEADS+hd] + ldst;
    v = v>0.f ? v : 0.2f*v;
    float mn = fmaxf(m_, v);
    z_ = z_*__expf(m_-mn) + __expf(v-mn);
    m_ = mn;
  }
  for (int o=32;o;o>>=1){
    float mo = __shfl_down(m_,o), zo = __shfl_down(z_,o);
    float mn = fmaxf(m_, mo);
    z_ = z_*__expf(m_-mn) + zo*__expf(mo-mn);
    m_ = mn;
  }
  float mx = __shfl(m_,0);
  float zs = __shfl(z_,0);
  float inv = 1.f/(zs+1e-16f);
  // ---- weighted accumulate: pipelined batch-4 ----
  float acc[8] = {0,0,0,0,0,0,0,0};
  const ushort* hb = hbf + hd*HIDC + lane*8;
  int i = beg;
  if (i+4 <= end){
    uint4 g0[4]; float lv0[4];
    #pragma unroll
    for (int q=0;q<4;q++){
      int s = slist[i+q];
      g0[q] = *(const uint4*)(hb + (size_t)s*FW);
      lv0[q] = lgs[s*HEADS+hd];
    }
    i += 4;
    for (; i+4<=end; i+=4){
      uint4 g1[4]; float lv1[4];
      #pragma unroll
      for (int q=0;q<4;q++){
        int s = slist[i+q];
        g1[q] = *(const uint4*)(hb + (size_t)s*FW);
        lv1[q] = lgs[s*HEADS+hd];
      }
      #pragma unroll
      for (int q=0;q<4;q++){
        float v = lv0[q] + ldst; v = v>0.f ? v : 0.2f*v;
        fma8(acc, g0[q], __expf(v-mx)*inv);
      }
      #pragma unroll
      for (int q=0;q<4;q++){ g0[q]=g1[q]; lv0[q]=lv1[q]; }
    }
    #pragma unroll
    for (int q=0;q<4;q++){
      float v = lv0[q] + ldst; v = v>0.f ? v : 0.2f*v;
      fma8(acc, g0[q], __expf(v-mx)*inv);
    }
  }
  for (; i<end; i++){
    int s = slist[i];
    uint4 g = *(const uint4*)(hb + (size_t)s*FW);
    float v = lgs[s*HEADS+hd] + ldst; v = v>0.f ? v : 0.2f*v;
    fma8(acc, g, __expf(v-mx)*inv);
  }
  size_t off = (size_t)n*FW + hd*HIDC + lane*8;
  pack8(Hbf + off, acc);
}

// ---------------- SpMM: scalar-uniform edge loop, pipelined batch-4 ----------------
__global__ __launch_bounds__(256) void spmm_bf(const ushort* __restrict__ Hbf,
    ushort* __restrict__ Phi,
    const int* __restrict__ rowptr, const int2* __restrict__ cw, const float* __restrict__ dinv){
  int t = threadIdx.x;
  int wv = __builtin_amdgcn_readfirstlane(t>>6);
  int lane = t&63;
  int b = blockIdx.x;
  int ck = __builtin_amdgcn_readfirstlane(b & 3);
  int n = ((b>>2)<<2) + wv;
  int f = (ck<<9) + lane*8;
  float di = dinv[n];
  float acc[8] = {0,0,0,0,0,0,0,0};
  const ushort* hb = Hbf + f;
  uint4 self = *(const uint4*)(hb + (size_t)n*FW);
  fma8(acc, self, di*di);
  int beg = __builtin_amdgcn_readfirstlane(rowptr[n]);
  int end = __builtin_amdgcn_readfirstlane(rowptr[n+1]);
  int i = beg;
  if (i+4 <= end){
    int2 e0[4]; uint4 g0[4];
    #pragma unroll
    for (int q=0;q<4;q++) e0[q] = cw[i+q];
    #pragma unroll
    for (int q=0;q<4;q++) g0[q] = *(const uint4*)(hb + (size_t)e0[q].x*FW);
    i += 4;
    for (; i+4<=end; i+=4){
      int2 e1[4]; uint4 g1[4];
      #pragma unroll
      for (int q=0;q<4;q++) e1[q] = cw[i+q];
      #pragma unroll
      for (int q=0;q<4;q++) g1[q] = *(const uint4*)(hb + (size_t)e1[q].x*FW);
      #pragma unroll
      for (int q=0;q<4;q++) fma8(acc, g0[q], di*__int_as_float(e0[q].y));
      #pragma unroll
      for (int q=0;q<4;q++){ e0[q]=e1[q]; g0[q]=g1[q]; }
    }
    #pragma unroll
    for (int q=0;q<4;q++) fma8(acc, g0[q], di*__int_as_float(e0[q].y));
  }
  for (; i<end; i++){
    int2 e = cw[i];
    uint4 g = *(const uint4*)(hb + (size_t)e.x*FW);
    fma8(acc, g, di*__int_as_float(e.y));
  }
  pack8(Phi + (size_t)n*FW + f, acc);
}

// ---------------- pooling ----------------
__global__ __launch_bounds__(256) void pool_accum(const ushort* __restrict__ Hb,
    const int* __restrict__ batch, float* __restrict__ psum){
  int d2 = blockIdx.y*256 + threadIdx.x;   // feature-pair index
  int n0 = blockIdx.x*32;
  int g = batch[n0];
  float s0 = 0.f, s1 = 0.f;
  for (int k=0;k<32;k++){
    int n = n0+k;
    int gn = batch[n];
    if (gn != g){
      atomicAdd(&psum[(size_t)g*FW + d2*2],   s0);
      atomicAdd(&psum[(size_t)g*FW + d2*2+1], s1);
      s0=0.f; s1=0.f; g=gn;
    }
    uint v = *(const uint*)(Hb + (size_t)n*FW + d2*2);
    s0 += bf2f((ushort)(v&0xffff));
    s1 += bf2f((ushort)(v>>16));
  }
  atomicAdd(&psum[(size_t)g*FW + d2*2],   s0);
  atomicAdd(&psum[(size_t)g*FW + d2*2+1], s1);
}
__global__ __launch_bounds__(256) void final_out(const float* __restrict__ psum,
    const int* __restrict__ goff,
    const float* __restrict__ fc_w, const float* __restrict__ fc_b, float* __restrict__ out){
  int g = blockIdx.x; int t = threadIdx.x;
  float cinv = 0.25f / fmaxf((float)(goff[g+1]-goff[g]), 1.f);
  float p = 0.f;
  for (int d=t; d<HIDC; d+=256){
    float f = cinv*(psum[(size_t)g*FW+d] + psum[(size_t)g*FW+HIDC+d]
                  + psum[(size_t)g*FW+2*HIDC+d] + psum[(size_t)g*FW+3*HIDC+d]);
    p += f*fc_w[d];
  }
  __shared__ float red[4];
  for (int off=32; off; off>>=1) p += __shfl_down(p,off);
  if ((t&63)==0) red[t>>6]=p;
  __syncthreads();
  if (t==0) out[g] = red[0]+red[1]+red[2]+red[3] + fc_b[0];
}

extern "C" void kernel_launch(void* const* d_in, const int* in_sizes, int n_in,
                              void* d_out, int out_size, void* d_ws, size_t ws_size,
                              hipStream_t stream){
  const float* x      = (const float*)d_in[0];
  const int*   ei     = (const int*)d_in[1];
  const int*   batch  = (const int*)d_in[2];
  const float* W_gat  = (const float*)d_in[3];
  const float* a_src  = (const float*)d_in[4];
  const float* a_dst  = (const float*)d_in[5];
  const float* W_gcn  = (const float*)d_in[6];
  const float* fc_w   = (const float*)d_in[7];
  const float* fc_b   = (const float*)d_in[8];
  float* out = (float*)d_out;
  const int* src = ei;
  const int* dst = ei + Ee;

  char* w = (char*)d_ws;
  size_t off = 0;
  auto alloc = [&](size_t bytes)->char*{ char* p = w + off; off = (off + bytes + 255) & ~(size_t)255; return p; };
  ushort* hbf    = (ushort*)alloc((size_t)Nn*FW*2);       // GAT projection; REUSED as Phi
  ushort* Hbf    = (ushort*)alloc((size_t)Nn*FW*2);       // bf16 node features H (residual trunk)
  ushort* WgatT  = (ushort*)alloc((size_t)HEADS*INC*HIDC*2);
  ushort* WgcnT  = (ushort*)alloc((size_t)NLAY*HIDC*HIDC*2);
  // ---- contiguous zero-init region (single memset) ----
  int* indeg    = (int*)alloc(Nn*4);
  int* fill_d   = (int*)alloc(Nn*4);
  int* cnt_s    = (int*)alloc(Nn*4);
  int* fill_s   = (int*)alloc(Nn*4);
  float* psum   = (float*)alloc((size_t)GG*FW*4);
  float* lgs    = (float*)alloc((size_t)Nn*HEADS*4);      // atomically accumulated
  float* lgd    = (float*)alloc((size_t)Nn*HEADS*4);
  unsigned int* bitmap = (unsigned int*)alloc((size_t)Nn*Nn/8);
  size_t zero_bytes = (size_t)Nn*4*4 + (size_t)GG*FW*4 + (size_t)Nn*HEADS*4*2 + (size_t)Nn*Nn/8;
  // ---- rest ----
  int* rowptr_d = (int*)alloc((Nn+1)*4);
  int* slist    = (int*)alloc(Ee*4);
  int* rowptr_s = (int*)alloc((Nn+1)*4);
  int2* cwlist  = (int2*)alloc((size_t)Ee*8);
  int* flag     = (int*)alloc(Ee*4);
  float* dinv   = (float*)alloc(Nn*4);
  int* goff     = (int*)alloc((GG+1)*4);
  ushort* Phi   = hbf;

  hipMemsetAsync(indeg, 0, zero_bytes, stream);

  // ---- fused prep (W transposes + edge pass 1) ----
  prep<<<2304,256,0,stream>>>(W_gat, WgatT, W_gcn, WgcnT,
                              src, dst, indeg, bitmap, cnt_s, flag);

  // ---- CSR scans ----
  scan3<<<3,1024,0,stream>>>(indeg, rowptr_d, cnt_s, rowptr_s, dinv, batch, goff);

  // ---- GAT projection gemm (fp32 A, fused logits) + edge scatter ----
  gat_gemm_ep2<<<1536,256,0,stream>>>(x, WgatT, hbf, a_src, a_dst, lgs, lgd,
      src, dst, flag, rowptr_d, fill_d, slist, rowptr_s, fill_s, cwlist, dinv);

  gat_aggregate<<<Nn,256,0,stream>>>(hbf, lgs, lgd, rowptr_d, slist, Hbf);

  // ---- residual GCN layers (bf16 trunk) ----
  for (int l=0;l<NLAY;l++){
    spmm_bf<<<Nn,256,0,stream>>>(Hbf, Phi, rowptr_s, cwlist, dinv);
    gemm_bf<<<dim3(HIDC/128, (Nn*HEADS)/64),256,0,stream>>>(Phi,
        WgcnT + (size_t)l*HIDC*HIDC,
        Hbf, Hbf, HIDC, HIDC, 1);
  }

  // ---- pooling + FC ----
  pool_accum<<<dim3(Nn/32, FW/512),256,0,stream>>>(Hbf, batch, psum);
  final_out<<<GG,256,0,stream>>>(psum, goff, fc_w, fc_b, out);
}

// Round 17
// 360.869 us; speedup vs baseline: 1.0321x; 1.0321x over previous
//
#include <hip/hip_runtime.h>
#include <cstdint>
#include <cstddef>

#define Nn    4096
#define Ee    131072
#define INC   512
#define HIDC  512
#define HEADS 4
#define NLAY  3
#define GG    16
#define FW    2048   // HEADS*HIDC
#define ALDS  2112   // A LDS tile: 4 kq blocks x 66 rows x 8 shorts (bank-staggered)
#define BLDS  4160   // B LDS tile: 4 kq blocks x 130 rows x 8 shorts

typedef __attribute__((ext_vector_type(8))) short bfrag;   // 8 bf16 (4 VGPRs)
typedef __attribute__((ext_vector_type(4))) float ffrag;   // 4 fp32 acc

__device__ __forceinline__ ushort f2bf(float v){
  uint u = __builtin_bit_cast(uint, v);
  u += 0x7fffu + ((u>>16)&1u);          // RNE
  return (ushort)(u>>16);
}
__device__ __forceinline__ float bf2f(ushort s){
  uint u = ((uint)s)<<16; return __builtin_bit_cast(float, u);
}
// acc[0..7] += w * unpack8(bf16x8 in uint4)
__device__ __forceinline__ void fma8(float* acc, uint4 g, float w){
  uint u[4] = {g.x, g.y, g.z, g.w};
  #pragma unroll
  for (int q=0;q<4;q++){
    float lo = __builtin_bit_cast(float, u[q]<<16);
    float hi = __builtin_bit_cast(float, u[q] & 0xffff0000u);
    acc[2*q]   += w*lo;
    acc[2*q+1] += w*hi;
  }
}
__device__ __forceinline__ void pack8(void* p, const float* a){
  uint4 o;
  o.x = (uint)f2bf(a[0]) | ((uint)f2bf(a[1])<<16);
  o.y = (uint)f2bf(a[2]) | ((uint)f2bf(a[3])<<16);
  o.z = (uint)f2bf(a[4]) | ((uint)f2bf(a[5])<<16);
  o.w = (uint)f2bf(a[6]) | ((uint)f2bf(a[7])<<16);
  *(uint4*)p = o;
}
// pack 8 fp32 (two float4, memory order) -> 8 bf16 in uint4
__device__ __forceinline__ uint4 cvt8(float4 a, float4 b){
  uint4 o;
  o.x = (uint)f2bf(a.x) | ((uint)f2bf(a.y)<<16);
  o.y = (uint)f2bf(a.z) | ((uint)f2bf(a.w)<<16);
  o.z = (uint)f2bf(b.x) | ((uint)f2bf(b.y)<<16);
  o.w = (uint)f2bf(b.z) | ((uint)f2bf(b.w)<<16);
  return o;
}

// ---------------- fused prep: W transposes->bf16 | edge pass 1 ----------------
// blocks [0,1792): tbf (7 z-slices: 4 gat + 3 gcn); [1792,2304): edge_pass1
__global__ __launch_bounds__(256) void prep(
    const float* __restrict__ Wgat, ushort* __restrict__ Tgat,
    const float* __restrict__ Wgcn, ushort* __restrict__ Tgcn,
    const int* __restrict__ src, const int* __restrict__ dst,
    int* __restrict__ indeg, unsigned int* __restrict__ bitmap,
    int* __restrict__ cnt_s, int* __restrict__ flag){
  __shared__ float tile[32][33];
  int b = blockIdx.x, t = threadIdx.x;
  if (b < 1792){
    int z = b >> 8, xy = b & 255;
    const float* W; ushort* T; int bb;
    if (z < 4){ W = Wgat; T = Tgat; bb = z; } else { W = Wgcn; T = Tgcn; bb = z-4; }
    int r0 = (xy>>4)*32, c0 = (xy&15)*32;
    int i = t>>3, j0 = (t&7)*4;
    const float* Wb = W + (size_t)bb*512*512;
    float4 v = *(const float4*)(Wb + (size_t)(r0+i)*512 + c0 + j0);
    tile[i][j0]=v.x; tile[i][j0+1]=v.y; tile[i][j0+2]=v.z; tile[i][j0+3]=v.w;
    __syncthreads();
    ushort* o = T + (size_t)bb*512*512 + (size_t)(c0+i)*512 + r0 + j0;
    #pragma unroll
    for (int q=0;q<4;q++) o[q] = f2bf(tile[j0+q][i]);
  } else {
    int e = (b-1792)*256 + t; if (e>=Ee) return;
    int s = src[e], d = dst[e];
    atomicAdd(&indeg[d],1);
    unsigned int key = (unsigned int)s*Nn + (unsigned int)d;
    unsigned int bit = 1u<<(key&31);
    unsigned int old = atomicOr(&bitmap[key>>5], bit);
    int f = (old & bit) ? 0 : 1;
    flag[e] = f;
    if (f) atomicAdd(&cnt_s[s],1);
  }
}

// ---------------- bf16 MFMA GEMM core: C = A@B^T, 64(M)x128(N) tile, LDS double-buffer ----------------
// Bank-staggered LDS (kq stride A=66 rows, B=130 rows -> bank +8/kq on staging writes).
// AF32: A operand read as fp32, converted to bf16 in registers (same f2bf rounding).
template<bool AF32>
__device__ __forceinline__ void gemm_core(
    const void* __restrict__ Av, const ushort* __restrict__ B,
    const ushort* Res, ushort* Cb,
    int N, int K, int relu_res, int m0, int n0,
    ushort* Ah, ushort* Bh)
{
  int t = threadIdx.x;
  int srA = t>>2, kqA = t&3;
  int wA = (kqA*66 + srA)*8;
  int srB = t>>1, cB = t&1;
  const ushort* pB = B + (size_t)(n0+srB)*K + cB*16;
  int wB0 = ((2*cB)*130 + srB)*8;
  int wB1 = wB0 + 130*8;

  int wave = t>>6, lane = t&63;
  int wm = (wave&1)*32, wn = (wave>>1)*64;
  int lm = lane&15, quad = lane>>4;

  ffrag acc[2][4];
  #pragma unroll
  for (int i=0;i<2;i++){
    #pragma unroll
    for (int j=0;j<4;j++) acc[i][j] = (ffrag){0.f,0.f,0.f,0.f};
  }

  const ushort* pA16 = (const ushort*)Av + (size_t)(m0+srA)*K + kqA*8;
  const float*  pA32 = (const float*)Av  + (size_t)(m0+srA)*K + kqA*8;

  uint4 ra; float4 raf0, raf1;
  if (AF32){ raf0 = *(const float4*)(pA32); raf1 = *(const float4*)(pA32+4); }
  else     { ra = *(const uint4*)(pA16); }
  uint4 rb0 = *(const uint4*)(pB);  uint4 rb1 = *(const uint4*)(pB+8);
  *(uint4*)&Ah[wA]  = AF32 ? cvt8(raf0, raf1) : ra;
  *(uint4*)&Bh[wB0] = rb0; *(uint4*)&Bh[wB1] = rb1;
  if (K > 32){
    if (AF32){ raf0 = *(const float4*)(pA32+32); raf1 = *(const float4*)(pA32+36); }
    else     { ra = *(const uint4*)(pA16+32); }
    rb0 = *(const uint4*)(pB+32); rb1 = *(const uint4*)(pB+40);
  }
  __syncthreads();

  for (int k0 = 0; k0 < K; k0 += 32){
    int cur = (k0>>5)&1, nxt = cur^1;
    const ushort* Ac = Ah + cur*ALDS;
    const ushort* Bc = Bh + cur*BLDS;
    bfrag af[2];
    #pragma unroll
    for (int mt=0; mt<2; mt++)
      af[mt] = *(const bfrag*)&Ac[(quad*66 + wm + mt*16 + lm)*8];
    #pragma unroll
    for (int nt=0; nt<4; nt++){
      bfrag bf = *(const bfrag*)&Bc[(quad*130 + wn + nt*16 + lm)*8];
      #pragma unroll
      for (int mt=0; mt<2; mt++)
        acc[mt][nt] = __builtin_amdgcn_mfma_f32_16x16x32_bf16(af[mt], bf, acc[mt][nt], 0,0,0);
    }
    if (k0+32 < K){
      *(uint4*)&Ah[nxt*ALDS + wA]  = AF32 ? cvt8(raf0, raf1) : ra;
      *(uint4*)&Bh[nxt*BLDS + wB0] = rb0; *(uint4*)&Bh[nxt*BLDS + wB1] = rb1;
      if (k0+64 < K){
        if (AF32){ raf0 = *(const float4*)(pA32+k0+64); raf1 = *(const float4*)(pA32+k0+68); }
        else     { ra = *(const uint4*)(pA16+k0+64); }
        rb0 = *(const uint4*)(pB+k0+64); rb1 = *(const uint4*)(pB+k0+72);
      }
    }
    __syncthreads();
  }

  #pragma unroll
  for (int mt=0; mt<2; mt++){
    #pragma unroll
    for (int nt=0; nt<4; nt++){
      #pragma unroll
      for (int r=0;r<4;r++){
        int grow = m0 + wm + mt*16 + quad*4 + r;
        int gcol = n0 + wn + nt*16 + lm;
        size_t off = (size_t)grow*N + gcol;
        float v = acc[mt][nt][r];
        if (relu_res) v = fmaxf(v,0.f) + bf2f(Res[off]);
        Cb[off] = f2bf(v);
      }
    }
  }
}

__global__ __launch_bounds__(256) void gemm_bf(
    const ushort* __restrict__ A, const ushort* __restrict__ B,
    const ushort* Res, ushort* Cb,
    int N, int K, int relu_res)
{
  __shared__ __align__(16) ushort Ah[2*ALDS];
  __shared__ __align__(16) ushort Bh[2*BLDS];
  gemm_core<false>(A, B, Res, Cb, N, K, relu_res,
                   blockIdx.y*64, blockIdx.x*128, Ah, Bh);
}

// ---------------- fused: GAT projection gemm (fp32 A) + edge scatter ----------------
__global__ __launch_bounds__(256) void gat_gemm_ep2(
    const float* __restrict__ x, const ushort* __restrict__ WgatT, ushort* __restrict__ hbf,
    const int* __restrict__ src, const int* __restrict__ dst, const int* __restrict__ flag,
    const int* __restrict__ rp_d, int* __restrict__ fill_d, int* __restrict__ slist,
    const int* __restrict__ rp_s, int* __restrict__ fill_s, int2* __restrict__ cw,
    const float* __restrict__ dinv)
{
  __shared__ __align__(16) ushort Ah[2*ALDS];
  __shared__ __align__(16) ushort Bh[2*BLDS];
  int b = blockIdx.x;
  if (b < 1024){
    int m0 = (b>>4)*64, n0 = (b&15)*128;   // M=Nn (64 tiles), N=FW (16 tiles)
    gemm_core<true>(x, WgatT, nullptr, hbf, FW, INC, 0, m0, n0, Ah, Bh);
  } else {
    int e = (b-1024)*256 + threadIdx.x; if (e>=Ee) return;
    int s = src[e], d = dst[e];
    int p = atomicAdd(&fill_d[d],1); slist[rp_d[d]+p] = s;
    if (flag[e]){
      int q = atomicAdd(&fill_s[s],1);
      cw[rp_s[s]+q] = make_int2(d, __float_as_int(dinv[d]));
    }
  }
}

// ---------------- attention logits per (node,head) ----------------
__global__ __launch_bounds__(256) void compute_lg(const ushort* __restrict__ hbf,
    const float* __restrict__ a_src, const float* __restrict__ a_dst,
    float* __restrict__ lgs, float* __restrict__ lgd){
  int n = blockIdx.x; int t = threadIdx.x;
  int hd = t>>6, lane = t&63;
  uint4 g = *(const uint4*)(hbf + (size_t)n*FW + hd*HIDC + lane*8);
  float h[8] = {0,0,0,0,0,0,0,0};
  fma8(h, g, 1.0f);
  float4 as0 = *(const float4*)(a_src + hd*HIDC + lane*8);
  float4 as1 = *(const float4*)(a_src + hd*HIDC + lane*8 + 4);
  float4 ad0 = *(const float4*)(a_dst + hd*HIDC + lane*8);
  float4 ad1 = *(const float4*)(a_dst + hd*HIDC + lane*8 + 4);
  float s1 = h[0]*as0.x + h[1]*as0.y + h[2]*as0.z + h[3]*as0.w
           + h[4]*as1.x + h[5]*as1.y + h[6]*as1.z + h[7]*as1.w;
  float s2 = h[0]*ad0.x + h[1]*ad0.y + h[2]*ad0.z + h[3]*ad0.w
           + h[4]*ad1.x + h[5]*ad1.y + h[6]*ad1.z + h[7]*ad1.w;
  for (int off=32; off; off>>=1){ s1 += __shfl_down(s1,off); s2 += __shfl_down(s2,off); }
  if (lane==0){ lgs[n*HEADS+hd]=s1; lgd[n*HEADS+hd]=s2; }
}

// ---------------- scan3: block0 scan indeg; block1 scan cnt_s + dinv; block2 goff ----------------
__global__ __launch_bounds__(1024) void scan3(const int* __restrict__ indeg, int* __restrict__ rp_d,
    const int* __restrict__ cnt_s, int* __restrict__ rp_s, float* __restrict__ dinv,
    const int* __restrict__ batch, int* __restrict__ goff){
  __shared__ int sums[1024];
  __shared__ int cnt2[GG];
  int t = threadIdx.x;
  if (blockIdx.x == 2){
    if (t<GG) cnt2[t]=0;
    __syncthreads();
    for (int i=t;i<Nn;i+=1024) atomicAdd(&cnt2[batch[i]],1);
    __syncthreads();
    if (t==0){ int run=0; for (int g=0; g<GG; g++){ goff[g]=run; run+=cnt2[g]; } goff[GG]=run; }
    return;
  }
  const int* cnt = blockIdx.x ? cnt_s : indeg;
  int* rowptr    = blockIdx.x ? rp_s  : rp_d;
  int v[4]; int s=0;
  #pragma unroll
  for (int i=0;i<4;i++){ int idx=t*4+i; v[i] = cnt[idx]; s+=v[i]; }
  sums[t]=s; __syncthreads();
  for (int off=1; off<1024; off<<=1){
    int other = (t>=off)? sums[t-off] : 0;
    __syncthreads();
    sums[t] += other;
    __syncthreads();
  }
  int run = (t>0)? sums[t-1] : 0;
  #pragma unroll
  for (int i=0;i<4;i++){
    int idx=t*4+i; rowptr[idx]=run; run+=v[i];
    if (blockIdx.x) dinv[idx] = 1.0f/sqrtf((float)(1+v[i]));
  }
  if (t==1023) rowptr[Nn]=sums[1023];
}

// ---------------- GAT softmax-aggregate: block = (4 nodes) x (1 head), wave = node ----------------
__global__ __launch_bounds__(256) void gat_aggregate(const ushort* __restrict__ hbf,
    const float* __restrict__ lgs, const float* __restrict__ lgd,
    const int* __restrict__ rowptr, const int* __restrict__ slist,
    ushort* __restrict__ Hbf){
  int t = threadIdx.x;
  int wv = __builtin_amdgcn_readfirstlane(t>>6);
  int lane = t&63;
  int b = blockIdx.x;
  int hd = __builtin_amdgcn_readfirstlane(b & 3);
  int n = ((b>>2)<<2) + wv;
  int beg = __builtin_amdgcn_readfirstlane(rowptr[n]);
  int end = __builtin_amdgcn_readfirstlane(rowptr[n+1]);
  int deg = end - beg;
  float ldst = lgd[n*HEADS+hd];
  // ---- single-pass online softmax (m,z), lane-parallel ----
  float m_ = -3.4e38f, z_ = 0.f;
  for (int i=lane; i<deg; i+=64){
    int s = slist[beg+i];
    float v = lgs[s*HEADS+hd] + ldst;
    v = v>0.f ? v : 0.2f*v;
    float mn = fmaxf(m_, v);
    z_ = z_*__expf(m_-mn) + __expf(v-mn);
    m_ = mn;
  }
  for (int o=32;o;o>>=1){
    float mo = __shfl_down(m_,o), zo = __shfl_down(z_,o);
    float mn = fmaxf(m_, mo);
    z_ = z_*__expf(m_-mn) + zo*__expf(mo-mn);
    m_ = mn;
  }
  float mx = __shfl(m_,0);
  float zs = __shfl(z_,0);
  float inv = 1.f/(zs+1e-16f);
  // ---- weighted accumulate: pipelined batch-4 ----
  float acc[8] = {0,0,0,0,0,0,0,0};
  const ushort* hb = hbf + hd*HIDC + lane*8;
  int i = beg;
  if (i+4 <= end){
    uint4 g0[4]; float lv0[4];
    #pragma unroll
    for (int q=0;q<4;q++){
      int s = slist[i+q];
      g0[q] = *(const uint4*)(hb + (size_t)s*FW);
      lv0[q] = lgs[s*HEADS+hd];
    }
    i += 4;
    for (; i+4<=end; i+=4){
      uint4 g1[4]; float lv1[4];
      #pragma unroll
      for (int q=0;q<4;q++){
        int s = slist[i+q];
        g1[q] = *(const uint4*)(hb + (size_t)s*FW);
        lv1[q] = lgs[s*HEADS+hd];
      }
      #pragma unroll
      for (int q=0;q<4;q++){
        float v = lv0[q] + ldst; v = v>0.f ? v : 0.2f*v;
        fma8(acc, g0[q], __expf(v-mx)*inv);
      }
      #pragma unroll
      for (int q=0;q<4;q++){ g0[q]=g1[q]; lv0[q]=lv1[q]; }
    }
    #pragma unroll
    for (int q=0;q<4;q++){
      float v = lv0[q] + ldst; v = v>0.f ? v : 0.2f*v;
      fma8(acc, g0[q], __expf(v-mx)*inv);
    }
  }
  for (; i<end; i++){
    int s = slist[i];
    uint4 g = *(const uint4*)(hb + (size_t)s*FW);
    float v = lgs[s*HEADS+hd] + ldst; v = v>0.f ? v : 0.2f*v;
    fma8(acc, g, __expf(v-mx)*inv);
  }
  size_t off = (size_t)n*FW + hd*HIDC + lane*8;
  pack8(Hbf + off, acc);
}

// ---------------- SpMM: scalar-uniform edge loop, pipelined batch-4 ----------------
__global__ __launch_bounds__(256) void spmm_bf(const ushort* __restrict__ Hbf,
    ushort* __restrict__ Phi,
    const int* __restrict__ rowptr, const int2* __restrict__ cw, const float* __restrict__ dinv){
  int t = threadIdx.x;
  int wv = __builtin_amdgcn_readfirstlane(t>>6);
  int lane = t&63;
  int b = blockIdx.x;
  int ck = __builtin_amdgcn_readfirstlane(b & 3);
  int n = ((b>>2)<<2) + wv;
  int f = (ck<<9) + lane*8;
  float di = dinv[n];
  float acc[8] = {0,0,0,0,0,0,0,0};
  const ushort* hb = Hbf + f;
  uint4 self = *(const uint4*)(hb + (size_t)n*FW);
  fma8(acc, self, di*di);
  int beg = __builtin_amdgcn_readfirstlane(rowptr[n]);
  int end = __builtin_amdgcn_readfirstlane(rowptr[n+1]);
  int i = beg;
  if (i+4 <= end){
    int2 e0[4]; uint4 g0[4];
    #pragma unroll
    for (int q=0;q<4;q++) e0[q] = cw[i+q];
    #pragma unroll
    for (int q=0;q<4;q++) g0[q] = *(const uint4*)(hb + (size_t)e0[q].x*FW);
    i += 4;
    for (; i+4<=end; i+=4){
      int2 e1[4]; uint4 g1[4];
      #pragma unroll
      for (int q=0;q<4;q++) e1[q] = cw[i+q];
      #pragma unroll
      for (int q=0;q<4;q++) g1[q] = *(const uint4*)(hb + (size_t)e1[q].x*FW);
      #pragma unroll
      for (int q=0;q<4;q++) fma8(acc, g0[q], di*__int_as_float(e0[q].y));
      #pragma unroll
      for (int q=0;q<4;q++){ e0[q]=e1[q]; g0[q]=g1[q]; }
    }
    #pragma unroll
    for (int q=0;q<4;q++) fma8(acc, g0[q], di*__int_as_float(e0[q].y));
  }
  for (; i<end; i++){
    int2 e = cw[i];
    uint4 g = *(const uint4*)(hb + (size_t)e.x*FW);
    fma8(acc, g, di*__int_as_float(e.y));
  }
  pack8(Phi + (size_t)n*FW + f, acc);
}

// ---------------- pooling ----------------
__global__ __launch_bounds__(256) void pool_accum(const ushort* __restrict__ Hb,
    const int* __restrict__ batch, float* __restrict__ psum){
  int d2 = blockIdx.y*256 + threadIdx.x;   // feature-pair index
  int n0 = blockIdx.x*32;
  int g = batch[n0];
  float s0 = 0.f, s1 = 0.f;
  for (int k=0;k<32;k++){
    int n = n0+k;
    int gn = batch[n];
    if (gn != g){
      atomicAdd(&psum[(size_t)g*FW + d2*2],   s0);
      atomicAdd(&psum[(size_t)g*FW + d2*2+1], s1);
      s0=0.f; s1=0.f; g=gn;
    }
    uint v = *(const uint*)(Hb + (size_t)n*FW + d2*2);
    s0 += bf2f((ushort)(v&0xffff));
    s1 += bf2f((ushort)(v>>16));
  }
  atomicAdd(&psum[(size_t)g*FW + d2*2],   s0);
  atomicAdd(&psum[(size_t)g*FW + d2*2+1], s1);
}
__global__ __launch_bounds__(256) void final_out(const float* __restrict__ psum,
    const int* __restrict__ goff,
    const float* __restrict__ fc_w, const float* __restrict__ fc_b, float* __restrict__ out){
  int g = blockIdx.x; int t = threadIdx.x;
  float cinv = 0.25f / fmaxf((float)(goff[g+1]-goff[g]), 1.f);
  float p = 0.f;
  for (int d=t; d<HIDC; d+=256){
    float f = cinv*(psum[(size_t)g*FW+d] + psum[(size_t)g*FW+HIDC+d]
                  + psum[(size_t)g*FW+2*HIDC+d] + psum[(size_t)g*FW+3*HIDC+d]);
    p += f*fc_w[d];
  }
  __shared__ float red[4];
  for (int off=32; off; off>>=1) p += __shfl_down(p,off);
  if ((t&63)==0) red[t>>6]=p;
  __syncthreads();
  if (t==0) out[g] = red[0]+red[1]+red[2]+red[3] + fc_b[0];
}

extern "C" void kernel_launch(void* const* d_in, const int* in_sizes, int n_in,
                              void* d_out, int out_size, void* d_ws, size_t ws_size,
                              hipStream_t stream){
  const float* x      = (const float*)d_in[0];
  const int*   ei     = (const int*)d_in[1];
  const int*   batch  = (const int*)d_in[2];
  const float* W_gat  = (const float*)d_in[3];
  const float* a_src  = (const float*)d_in[4];
  const float* a_dst  = (const float*)d_in[5];
  const float* W_gcn  = (const float*)d_in[6];
  const float* fc_w   = (const float*)d_in[7];
  const float* fc_b   = (const float*)d_in[8];
  float* out = (float*)d_out;
  const int* src = ei;
  const int* dst = ei + Ee;

  char* w = (char*)d_ws;
  size_t off = 0;
  auto alloc = [&](size_t bytes)->char*{ char* p = w + off; off = (off + bytes + 255) & ~(size_t)255; return p; };
  ushort* hbf    = (ushort*)alloc((size_t)Nn*FW*2);       // GAT projection; REUSED as Phi
  ushort* Hbf    = (ushort*)alloc((size_t)Nn*FW*2);       // bf16 node features H (residual trunk)
  ushort* WgatT  = (ushort*)alloc((size_t)HEADS*INC*HIDC*2);
  ushort* WgcnT  = (ushort*)alloc((size_t)NLAY*HIDC*HIDC*2);
  float* lgs    = (float*)alloc((size_t)Nn*HEADS*4);
  float* lgd    = (float*)alloc((size_t)Nn*HEADS*4);
  // ---- contiguous zero-init region (single memset) ----
  int* indeg    = (int*)alloc(Nn*4);
  int* fill_d   = (int*)alloc(Nn*4);
  int* cnt_s    = (int*)alloc(Nn*4);
  int* fill_s   = (int*)alloc(Nn*4);
  float* psum   = (float*)alloc((size_t)GG*FW*4);
  unsigned int* bitmap = (unsigned int*)alloc((size_t)Nn*Nn/8);
  size_t zero_bytes = (size_t)Nn*4*4 + (size_t)GG*FW*4 + (size_t)Nn*Nn/8;
  // ---- rest ----
  int* rowptr_d = (int*)alloc((Nn+1)*4);
  int* slist    = (int*)alloc(Ee*4);
  int* rowptr_s = (int*)alloc((Nn+1)*4);
  int2* cwlist  = (int2*)alloc((size_t)Ee*8);
  int* flag     = (int*)alloc(Ee*4);
  float* dinv   = (float*)alloc(Nn*4);
  int* goff     = (int*)alloc((GG+1)*4);
  ushort* Phi   = hbf;

  hipMemsetAsync(indeg, 0, zero_bytes, stream);

  // ---- fused prep (W transposes + edge pass 1) ----
  prep<<<2304,256,0,stream>>>(W_gat, WgatT, W_gcn, WgcnT,
                              src, dst, indeg, bitmap, cnt_s, flag);

  // ---- CSR scans ----
  scan3<<<3,1024,0,stream>>>(indeg, rowptr_d, cnt_s, rowptr_s, dinv, batch, goff);

  // ---- GAT projection gemm (fp32 A) + edge scatter, fused ----
  gat_gemm_ep2<<<1536,256,0,stream>>>(x, WgatT, hbf,
      src, dst, flag, rowptr_d, fill_d, slist, rowptr_s, fill_s, cwlist, dinv);

  compute_lg<<<Nn,256,0,stream>>>(hbf, a_src, a_dst, lgs, lgd);
  gat_aggregate<<<Nn,256,0,stream>>>(hbf, lgs, lgd, rowptr_d, slist, Hbf);

  // ---- residual GCN layers (bf16 trunk) ----
  for (int l=0;l<NLAY;l++){
    spmm_bf<<<Nn,256,0,stream>>>(Hbf, Phi, rowptr_s, cwlist, dinv);
    gemm_bf<<<dim3(HIDC/128, (Nn*HEADS)/64),256,0,stream>>>(Phi,
        WgcnT + (size_t)l*HIDC*HIDC,
        Hbf, Hbf, HIDC, HIDC, 1);
  }

  // ---- pooling + FC ----
  pool_accum<<<dim3(Nn/32, FW/512),256,0,stream>>>(Hbf, batch, psum);
  final_out<<<GG,256,0,stream>>>(psum, goff, fc_w, fc_b, out);
}

// Round 18
// 356.114 us; speedup vs baseline: 1.0458x; 1.0134x over previous
//
#include <hip/hip_runtime.h>
#include <cstdint>
#include <cstddef>

#define Nn    4096
#define Ee    131072
#define INC   512
#define HIDC  512
#define HEADS 4
#define NLAY  3
#define GG    16
#define FW    2048   // HEADS*HIDC
#define ALDS  2112   // A LDS tile: 4 kq blocks x 66 rows x 8 shorts (bank-staggered)
#define BLDS  4160   // B LDS tile: 4 kq blocks x 130 rows x 8 shorts

typedef __attribute__((ext_vector_type(8))) short bfrag;   // 8 bf16 (4 VGPRs)
typedef __attribute__((ext_vector_type(4))) float ffrag;   // 4 fp32 acc

__device__ __forceinline__ ushort f2bf(float v){
  uint u = __builtin_bit_cast(uint, v);
  u += 0x7fffu + ((u>>16)&1u);          // RNE
  return (ushort)(u>>16);
}
__device__ __forceinline__ float bf2f(ushort s){
  uint u = ((uint)s)<<16; return __builtin_bit_cast(float, u);
}
// acc[0..7] += w * unpack8(bf16x8 in uint4)
__device__ __forceinline__ void fma8(float* acc, uint4 g, float w){
  uint u[4] = {g.x, g.y, g.z, g.w};
  #pragma unroll
  for (int q=0;q<4;q++){
    float lo = __builtin_bit_cast(float, u[q]<<16);
    float hi = __builtin_bit_cast(float, u[q] & 0xffff0000u);
    acc[2*q]   += w*lo;
    acc[2*q+1] += w*hi;
  }
}
__device__ __forceinline__ void pack8(void* p, const float* a){
  uint4 o;
  o.x = (uint)f2bf(a[0]) | ((uint)f2bf(a[1])<<16);
  o.y = (uint)f2bf(a[2]) | ((uint)f2bf(a[3])<<16);
  o.z = (uint)f2bf(a[4]) | ((uint)f2bf(a[5])<<16);
  o.w = (uint)f2bf(a[6]) | ((uint)f2bf(a[7])<<16);
  *(uint4*)p = o;
}
// pack 8 fp32 (two float4, memory order) -> 8 bf16 in uint4
__device__ __forceinline__ uint4 cvt8(float4 a, float4 b){
  uint4 o;
  o.x = (uint)f2bf(a.x) | ((uint)f2bf(a.y)<<16);
  o.y = (uint)f2bf(a.z) | ((uint)f2bf(a.w)<<16);
  o.z = (uint)f2bf(b.x) | ((uint)f2bf(b.y)<<16);
  o.w = (uint)f2bf(b.z) | ((uint)f2bf(b.w)<<16);
  return o;
}

// ---------------- fused prep: W transposes->bf16 | edge pass 1 ----------------
__global__ __launch_bounds__(256) void prep(
    const float* __restrict__ Wgat, ushort* __restrict__ Tgat,
    const float* __restrict__ Wgcn, ushort* __restrict__ Tgcn,
    const int* __restrict__ src, const int* __restrict__ dst,
    int* __restrict__ indeg, unsigned int* __restrict__ bitmap,
    int* __restrict__ cnt_s, int* __restrict__ flag){
  __shared__ float tile[32][33];
  int b = blockIdx.x, t = threadIdx.x;
  if (b < 1792){
    int z = b >> 8, xy = b & 255;
    const float* W; ushort* T; int bb;
    if (z < 4){ W = Wgat; T = Tgat; bb = z; } else { W = Wgcn; T = Tgcn; bb = z-4; }
    int r0 = (xy>>4)*32, c0 = (xy&15)*32;
    int i = t>>3, j0 = (t&7)*4;
    const float* Wb = W + (size_t)bb*512*512;
    float4 v = *(const float4*)(Wb + (size_t)(r0+i)*512 + c0 + j0);
    tile[i][j0]=v.x; tile[i][j0+1]=v.y; tile[i][j0+2]=v.z; tile[i][j0+3]=v.w;
    __syncthreads();
    ushort* o = T + (size_t)bb*512*512 + (size_t)(c0+i)*512 + r0 + j0;
    #pragma unroll
    for (int q=0;q<4;q++) o[q] = f2bf(tile[j0+q][i]);
  } else {
    int e = (b-1792)*256 + t; if (e>=Ee) return;
    int s = src[e], d = dst[e];
    atomicAdd(&indeg[d],1);
    unsigned int key = (unsigned int)s*Nn + (unsigned int)d;
    unsigned int bit = 1u<<(key&31);
    unsigned int old = atomicOr(&bitmap[key>>5], bit);
    int f = (old & bit) ? 0 : 1;
    flag[e] = f;
    if (f) atomicAdd(&cnt_s[s],1);
  }
}

// ---------------- bf16 MFMA GEMM core: C = A@B^T, 64(M)x128(N) tile, LDS double-buffer ----------------
// Bank-staggered LDS; AF32 = fp32 A operand (register f2bf); Res prefetched BEFORE K-loop.
template<bool AF32>
__device__ __forceinline__ void gemm_core(
    const void* __restrict__ Av, const ushort* __restrict__ B,
    const ushort* Res, ushort* Cb,
    int N, int K, int relu_res, int m0, int n0,
    ushort* Ah, ushort* Bh)
{
  int t = threadIdx.x;
  int srA = t>>2, kqA = t&3;
  int wA = (kqA*66 + srA)*8;
  int srB = t>>1, cB = t&1;
  const ushort* pB = B + (size_t)(n0+srB)*K + cB*16;
  int wB0 = ((2*cB)*130 + srB)*8;
  int wB1 = wB0 + 130*8;

  int wave = t>>6, lane = t&63;
  int wm = (wave&1)*32, wn = (wave>>1)*64;
  int lm = lane&15, quad = lane>>4;

  // ---- prefetch Res (epilogue operand) before the K-loop ----
  ushort resv[2][4][4];
  if (relu_res){
    #pragma unroll
    for (int mt=0; mt<2; mt++)
      #pragma unroll
      for (int r=0;r<4;r++){
        int grow = m0 + wm + mt*16 + quad*4 + r;
        #pragma unroll
        for (int nt=0; nt<4; nt++){
          int gcol = n0 + wn + nt*16 + lm;
          resv[mt][nt][r] = Res[(size_t)grow*N + gcol];
        }
      }
  }

  ffrag acc[2][4];
  #pragma unroll
  for (int i=0;i<2;i++){
    #pragma unroll
    for (int j=0;j<4;j++) acc[i][j] = (ffrag){0.f,0.f,0.f,0.f};
  }

  const ushort* pA16 = (const ushort*)Av + (size_t)(m0+srA)*K + kqA*8;
  const float*  pA32 = (const float*)Av  + (size_t)(m0+srA)*K + kqA*8;

  uint4 ra; float4 raf0, raf1;
  if (AF32){ raf0 = *(const float4*)(pA32); raf1 = *(const float4*)(pA32+4); }
  else     { ra = *(const uint4*)(pA16); }
  uint4 rb0 = *(const uint4*)(pB);  uint4 rb1 = *(const uint4*)(pB+8);
  *(uint4*)&Ah[wA]  = AF32 ? cvt8(raf0, raf1) : ra;
  *(uint4*)&Bh[wB0] = rb0; *(uint4*)&Bh[wB1] = rb1;
  if (K > 32){
    if (AF32){ raf0 = *(const float4*)(pA32+32); raf1 = *(const float4*)(pA32+36); }
    else     { ra = *(const uint4*)(pA16+32); }
    rb0 = *(const uint4*)(pB+32); rb1 = *(const uint4*)(pB+40);
  }
  __syncthreads();

  for (int k0 = 0; k0 < K; k0 += 32){
    int cur = (k0>>5)&1, nxt = cur^1;
    const ushort* Ac = Ah + cur*ALDS;
    const ushort* Bc = Bh + cur*BLDS;
    bfrag af[2];
    #pragma unroll
    for (int mt=0; mt<2; mt++)
      af[mt] = *(const bfrag*)&Ac[(quad*66 + wm + mt*16 + lm)*8];
    #pragma unroll
    for (int nt=0; nt<4; nt++){
      bfrag bf = *(const bfrag*)&Bc[(quad*130 + wn + nt*16 + lm)*8];
      #pragma unroll
      for (int mt=0; mt<2; mt++)
        acc[mt][nt] = __builtin_amdgcn_mfma_f32_16x16x32_bf16(af[mt], bf, acc[mt][nt], 0,0,0);
    }
    if (k0+32 < K){
      *(uint4*)&Ah[nxt*ALDS + wA]  = AF32 ? cvt8(raf0, raf1) : ra;
      *(uint4*)&Bh[nxt*BLDS + wB0] = rb0; *(uint4*)&Bh[nxt*BLDS + wB1] = rb1;
      if (k0+64 < K){
        if (AF32){ raf0 = *(const float4*)(pA32+k0+64); raf1 = *(const float4*)(pA32+k0+68); }
        else     { ra = *(const uint4*)(pA16+k0+64); }
        rb0 = *(const uint4*)(pB+k0+64); rb1 = *(const uint4*)(pB+k0+72);
      }
    }
    __syncthreads();
  }

  #pragma unroll
  for (int mt=0; mt<2; mt++){
    #pragma unroll
    for (int nt=0; nt<4; nt++){
      #pragma unroll
      for (int r=0;r<4;r++){
        int grow = m0 + wm + mt*16 + quad*4 + r;
        int gcol = n0 + wn + nt*16 + lm;
        size_t off = (size_t)grow*N + gcol;
        float v = acc[mt][nt][r];
        if (relu_res) v = fmaxf(v,0.f) + bf2f(resv[mt][nt][r]);
        Cb[off] = f2bf(v);
      }
    }
  }
}

__global__ __launch_bounds__(256) void gemm_bf(
    const ushort* __restrict__ A, const ushort* __restrict__ B,
    const ushort* Res, ushort* Cb,
    int N, int K, int relu_res)
{
  __shared__ __align__(16) ushort Ah[2*ALDS];
  __shared__ __align__(16) ushort Bh[2*BLDS];
  gemm_core<false>(A, B, Res, Cb, N, K, relu_res,
                   blockIdx.y*64, blockIdx.x*128, Ah, Bh);
}

// ---------------- fused: GAT projection gemm (fp32 A) + edge scatter ----------------
__global__ __launch_bounds__(256) void gat_gemm_ep2(
    const float* __restrict__ x, const ushort* __restrict__ WgatT, ushort* __restrict__ hbf,
    const int* __restrict__ src, const int* __restrict__ dst, const int* __restrict__ flag,
    const int* __restrict__ rp_d, int* __restrict__ fill_d, int* __restrict__ slist,
    const int* __restrict__ rp_s, int* __restrict__ fill_s, int2* __restrict__ cw,
    const float* __restrict__ dinv)
{
  __shared__ __align__(16) ushort Ah[2*ALDS];
  __shared__ __align__(16) ushort Bh[2*BLDS];
  int b = blockIdx.x;
  if (b < 1024){
    int m0 = (b>>4)*64, n0 = (b&15)*128;   // M=Nn (64 tiles), N=FW (16 tiles)
    gemm_core<true>(x, WgatT, nullptr, hbf, FW, INC, 0, m0, n0, Ah, Bh);
  } else {
    int e = (b-1024)*256 + threadIdx.x; if (e>=Ee) return;
    int s = src[e], d = dst[e];
    int p = atomicAdd(&fill_d[d],1); slist[rp_d[d]+p] = s;
    if (flag[e]){
      int q = atomicAdd(&fill_s[s],1);
      cw[rp_s[s]+q] = make_int2(d, __float_as_int(dinv[d]));
    }
  }
}

// ---------------- attention logits per (node,head) ----------------
__global__ __launch_bounds__(256) void compute_lg(const ushort* __restrict__ hbf,
    const float* __restrict__ a_src, const float* __restrict__ a_dst,
    float* __restrict__ lgs, float* __restrict__ lgd){
  int n = blockIdx.x; int t = threadIdx.x;
  int hd = t>>6, lane = t&63;
  uint4 g = *(const uint4*)(hbf + (size_t)n*FW + hd*HIDC + lane*8);
  float h[8] = {0,0,0,0,0,0,0,0};
  fma8(h, g, 1.0f);
  float4 as0 = *(const float4*)(a_src + hd*HIDC + lane*8);
  float4 as1 = *(const float4*)(a_src + hd*HIDC + lane*8 + 4);
  float4 ad0 = *(const float4*)(a_dst + hd*HIDC + lane*8);
  float4 ad1 = *(const float4*)(a_dst + hd*HIDC + lane*8 + 4);
  float s1 = h[0]*as0.x + h[1]*as0.y + h[2]*as0.z + h[3]*as0.w
           + h[4]*as1.x + h[5]*as1.y + h[6]*as1.z + h[7]*as1.w;
  float s2 = h[0]*ad0.x + h[1]*ad0.y + h[2]*ad0.z + h[3]*ad0.w
           + h[4]*ad1.x + h[5]*ad1.y + h[6]*ad1.z + h[7]*ad1.w;
  for (int off=32; off; off>>=1){ s1 += __shfl_down(s1,off); s2 += __shfl_down(s2,off); }
  if (lane==0){ lgs[n*HEADS+hd]=s1; lgd[n*HEADS+hd]=s2; }
}

// ---------------- scan3 ----------------
__global__ __launch_bounds__(1024) void scan3(const int* __restrict__ indeg, int* __restrict__ rp_d,
    const int* __restrict__ cnt_s, int* __restrict__ rp_s, float* __restrict__ dinv,
    const int* __restrict__ batch, int* __restrict__ goff){
  __shared__ int sums[1024];
  __shared__ int cnt2[GG];
  int t = threadIdx.x;
  if (blockIdx.x == 2){
    if (t<GG) cnt2[t]=0;
    __syncthreads();
    for (int i=t;i<Nn;i+=1024) atomicAdd(&cnt2[batch[i]],1);
    __syncthreads();
    if (t==0){ int run=0; for (int g=0; g<GG; g++){ goff[g]=run; run+=cnt2[g]; } goff[GG]=run; }
    return;
  }
  const int* cnt = blockIdx.x ? cnt_s : indeg;
  int* rowptr    = blockIdx.x ? rp_s  : rp_d;
  int v[4]; int s=0;
  #pragma unroll
  for (int i=0;i<4;i++){ int idx=t*4+i; v[i] = cnt[idx]; s+=v[i]; }
  sums[t]=s; __syncthreads();
  for (int off=1; off<1024; off<<=1){
    int other = (t>=off)? sums[t-off] : 0;
    __syncthreads();
    sums[t] += other;
    __syncthreads();
  }
  int run = (t>0)? sums[t-1] : 0;
  #pragma unroll
  for (int i=0;i<4;i++){
    int idx=t*4+i; rowptr[idx]=run; run+=v[i];
    if (blockIdx.x) dinv[idx] = 1.0f/sqrtf((float)(1+v[i]));
  }
  if (t==1023) rowptr[Nn]=sums[1023];
}

// ---------------- GAT softmax-aggregate: depth-2 x batch-8 pipelined gathers ----------------
__global__ __launch_bounds__(256) void gat_aggregate(const ushort* __restrict__ hbf,
    const float* __restrict__ lgs, const float* __restrict__ lgd,
    const int* __restrict__ rowptr, const int* __restrict__ slist,
    ushort* __restrict__ Hbf){
  int t = threadIdx.x;
  int wv = __builtin_amdgcn_readfirstlane(t>>6);
  int lane = t&63;
  int b = blockIdx.x;
  int hd = __builtin_amdgcn_readfirstlane(b & 3);
  int n = ((b>>2)<<2) + wv;
  int beg = __builtin_amdgcn_readfirstlane(rowptr[n]);
  int end = __builtin_amdgcn_readfirstlane(rowptr[n+1]);
  int deg = end - beg;
  float ldst = lgd[n*HEADS+hd];
  // ---- single-pass online softmax (m,z), lane-parallel ----
  float m_ = -3.4e38f, z_ = 0.f;
  for (int i=lane; i<deg; i+=64){
    int s = slist[beg+i];
    float v = lgs[s*HEADS+hd] + ldst;
    v = v>0.f ? v : 0.2f*v;
    float mn = fmaxf(m_, v);
    z_ = z_*__expf(m_-mn) + __expf(v-mn);
    m_ = mn;
  }
  for (int o=32;o;o>>=1){
    float mo = __shfl_down(m_,o), zo = __shfl_down(z_,o);
    float mn = fmaxf(m_, mo);
    z_ = z_*__expf(m_-mn) + zo*__expf(mo-mn);
    m_ = mn;
  }
  float mx = __shfl(m_,0);
  float zs = __shfl(z_,0);
  float inv = 1.f/(zs+1e-16f);
  // ---- weighted accumulate: pipelined depth-2 x batch-8 ----
  float acc[8] = {0,0,0,0,0,0,0,0};
  const ushort* hb = hbf + hd*HIDC + lane*8;
  int i = beg;
  if (i+8 <= end){
    uint4 g0[8]; float lv0[8];
    #pragma unroll
    for (int q=0;q<8;q++){
      int s = slist[i+q];
      g0[q] = *(const uint4*)(hb + (size_t)s*FW);
      lv0[q] = lgs[s*HEADS+hd];
    }
    i += 8;
    for (; i+8<=end; i+=8){
      uint4 g1[8]; float lv1[8];
      #pragma unroll
      for (int q=0;q<8;q++){
        int s = slist[i+q];
        g1[q] = *(const uint4*)(hb + (size_t)s*FW);
        lv1[q] = lgs[s*HEADS+hd];
      }
      #pragma unroll
      for (int q=0;q<8;q++){
        float v = lv0[q] + ldst; v = v>0.f ? v : 0.2f*v;
        fma8(acc, g0[q], __expf(v-mx)*inv);
      }
      #pragma unroll
      for (int q=0;q<8;q++){ g0[q]=g1[q]; lv0[q]=lv1[q]; }
    }
    #pragma unroll
    for (int q=0;q<8;q++){
      float v = lv0[q] + ldst; v = v>0.f ? v : 0.2f*v;
      fma8(acc, g0[q], __expf(v-mx)*inv);
    }
  }
  for (; i<end; i++){
    int s = slist[i];
    uint4 g = *(const uint4*)(hb + (size_t)s*FW);
    float v = lgs[s*HEADS+hd] + ldst; v = v>0.f ? v : 0.2f*v;
    fma8(acc, g, __expf(v-mx)*inv);
  }
  size_t off = (size_t)n*FW + hd*HIDC + lane*8;
  pack8(Hbf + off, acc);
}

// ---------------- SpMM: scalar-uniform edge loop, pipelined depth-2 x batch-8 ----------------
__global__ __launch_bounds__(256) void spmm_bf(const ushort* __restrict__ Hbf,
    ushort* __restrict__ Phi,
    const int* __restrict__ rowptr, const int2* __restrict__ cw, const float* __restrict__ dinv){
  int t = threadIdx.x;
  int wv = __builtin_amdgcn_readfirstlane(t>>6);
  int lane = t&63;
  int b = blockIdx.x;
  int ck = __builtin_amdgcn_readfirstlane(b & 3);
  int n = ((b>>2)<<2) + wv;
  int f = (ck<<9) + lane*8;
  float di = dinv[n];
  float acc[8] = {0,0,0,0,0,0,0,0};
  const ushort* hb = Hbf + f;
  uint4 self = *(const uint4*)(hb + (size_t)n*FW);
  fma8(acc, self, di*di);
  int beg = __builtin_amdgcn_readfirstlane(rowptr[n]);
  int end = __builtin_amdgcn_readfirstlane(rowptr[n+1]);
  int i = beg;
  if (i+8 <= end){
    int2 e0[8]; uint4 g0[8];
    #pragma unroll
    for (int q=0;q<8;q++) e0[q] = cw[i+q];
    #pragma unroll
    for (int q=0;q<8;q++) g0[q] = *(const uint4*)(hb + (size_t)e0[q].x*FW);
    i += 8;
    for (; i+8<=end; i+=8){
      int2 e1[8]; uint4 g1[8];
      #pragma unroll
      for (int q=0;q<8;q++) e1[q] = cw[i+q];
      #pragma unroll
      for (int q=0;q<8;q++) g1[q] = *(const uint4*)(hb + (size_t)e1[q].x*FW);
      #pragma unroll
      for (int q=0;q<8;q++) fma8(acc, g0[q], di*__int_as_float(e0[q].y));
      #pragma unroll
      for (int q=0;q<8;q++){ e0[q]=e1[q]; g0[q]=g1[q]; }
    }
    #pragma unroll
    for (int q=0;q<8;q++) fma8(acc, g0[q], di*__int_as_float(e0[q].y));
  }
  for (; i<end; i++){
    int2 e = cw[i];
    uint4 g = *(const uint4*)(hb + (size_t)e.x*FW);
    fma8(acc, g, di*__int_as_float(e.y));
  }
  pack8(Phi + (size_t)n*FW + f, acc);
}

// ---------------- pooling ----------------
__global__ __launch_bounds__(256) void pool_accum(const ushort* __restrict__ Hb,
    const int* __restrict__ batch, float* __restrict__ psum){
  int d2 = blockIdx.y*256 + threadIdx.x;   // feature-pair index
  int n0 = blockIdx.x*32;
  int g = batch[n0];
  float s0 = 0.f, s1 = 0.f;
  for (int k=0;k<32;k++){
    int n = n0+k;
    int gn = batch[n];
    if (gn != g){
      atomicAdd(&psum[(size_t)g*FW + d2*2],   s0);
      atomicAdd(&psum[(size_t)g*FW + d2*2+1], s1);
      s0=0.f; s1=0.f; g=gn;
    }
    uint v = *(const uint*)(Hb + (size_t)n*FW + d2*2);
    s0 += bf2f((ushort)(v&0xffff));
    s1 += bf2f((ushort)(v>>16));
  }
  atomicAdd(&psum[(size_t)g*FW + d2*2],   s0);
  atomicAdd(&psum[(size_t)g*FW + d2*2+1], s1);
}
__global__ __launch_bounds__(256) void final_out(const float* __restrict__ psum,
    const int* __restrict__ goff,
    const float* __restrict__ fc_w, const float* __restrict__ fc_b, float* __restrict__ out){
  int g = blockIdx.x; int t = threadIdx.x;
  float cinv = 0.25f / fmaxf((float)(goff[g+1]-goff[g]), 1.f);
  float p = 0.f;
  for (int d=t; d<HIDC; d+=256){
    float f = cinv*(psum[(size_t)g*FW+d] + psum[(size_t)g*FW+HIDC+d]
                  + psum[(size_t)g*FW+2*HIDC+d] + psum[(size_t)g*FW+3*HIDC+d]);
    p += f*fc_w[d];
  }
  __shared__ float red[4];
  for (int off=32; off; off>>=1) p += __shfl_down(p,off);
  if ((t&63)==0) red[t>>6]=p;
  __syncthreads();
  if (t==0) out[g] = red[0]+red[1]+red[2]+red[3] + fc_b[0];
}

extern "C" void kernel_launch(void* const* d_in, const int* in_sizes, int n_in,
                              void* d_out, int out_size, void* d_ws, size_t ws_size,
                              hipStream_t stream){
  const float* x      = (const float*)d_in[0];
  const int*   ei     = (const int*)d_in[1];
  const int*   batch  = (const int*)d_in[2];
  const float* W_gat  = (const float*)d_in[3];
  const float* a_src  = (const float*)d_in[4];
  const float* a_dst  = (const float*)d_in[5];
  const float* W_gcn  = (const float*)d_in[6];
  const float* fc_w   = (const float*)d_in[7];
  const float* fc_b   = (const float*)d_in[8];
  float* out = (float*)d_out;
  const int* src = ei;
  const int* dst = ei + Ee;

  char* w = (char*)d_ws;
  size_t off = 0;
  auto alloc = [&](size_t bytes)->char*{ char* p = w + off; off = (off + bytes + 255) & ~(size_t)255; return p; };
  ushort* hbf    = (ushort*)alloc((size_t)Nn*FW*2);       // GAT projection; REUSED as Phi
  ushort* Hbf    = (ushort*)alloc((size_t)Nn*FW*2);       // bf16 node features H (residual trunk)
  ushort* WgatT  = (ushort*)alloc((size_t)HEADS*INC*HIDC*2);
  ushort* WgcnT  = (ushort*)alloc((size_t)NLAY*HIDC*HIDC*2);
  float* lgs    = (float*)alloc((size_t)Nn*HEADS*4);
  float* lgd    = (float*)alloc((size_t)Nn*HEADS*4);
  // ---- contiguous zero-init region (single memset) ----
  int* indeg    = (int*)alloc(Nn*4);
  int* fill_d   = (int*)alloc(Nn*4);
  int* cnt_s    = (int*)alloc(Nn*4);
  int* fill_s   = (int*)alloc(Nn*4);
  float* psum   = (float*)alloc((size_t)GG*FW*4);
  unsigned int* bitmap = (unsigned int*)alloc((size_t)Nn*Nn/8);
  size_t zero_bytes = (size_t)Nn*4*4 + (size_t)GG*FW*4 + (size_t)Nn*Nn/8;
  // ---- rest ----
  int* rowptr_d = (int*)alloc((Nn+1)*4);
  int* slist    = (int*)alloc(Ee*4);
  int* rowptr_s = (int*)alloc((Nn+1)*4);
  int2* cwlist  = (int2*)alloc((size_t)Ee*8);
  int* flag     = (int*)alloc(Ee*4);
  float* dinv   = (float*)alloc(Nn*4);
  int* goff     = (int*)alloc((GG+1)*4);
  ushort* Phi   = hbf;

  hipMemsetAsync(indeg, 0, zero_bytes, stream);

  // ---- fused prep (W transposes + edge pass 1) ----
  prep<<<2304,256,0,stream>>>(W_gat, WgatT, W_gcn, WgcnT,
                              src, dst, indeg, bitmap, cnt_s, flag);

  // ---- CSR scans ----
  scan3<<<3,1024,0,stream>>>(indeg, rowptr_d, cnt_s, rowptr_s, dinv, batch, goff);

  // ---- GAT projection gemm (fp32 A) + edge scatter, fused ----
  gat_gemm_ep2<<<1536,256,0,stream>>>(x, WgatT, hbf,
      src, dst, flag, rowptr_d, fill_d, slist, rowptr_s, fill_s, cwlist, dinv);

  compute_lg<<<Nn,256,0,stream>>>(hbf, a_src, a_dst, lgs, lgd);
  gat_aggregate<<<Nn,256,0,stream>>>(hbf, lgs, lgd, rowptr_d, slist, Hbf);

  // ---- residual GCN layers (bf16 trunk) ----
  for (int l=0;l<NLAY;l++){
    spmm_bf<<<Nn,256,0,stream>>>(Hbf, Phi, rowptr_s, cwlist, dinv);
    gemm_bf<<<dim3(HIDC/128, (Nn*HEADS)/64),256,0,stream>>>(Phi,
        WgcnT + (size_t)l*HIDC*HIDC,
        Hbf, Hbf, HIDC, HIDC, 1);
  }

  // ---- pooling + FC ----
  pool_accum<<<dim3(Nn/32, FW/512),256,0,stream>>>(Hbf, batch, psum);
  final_out<<<GG,256,0,stream>>>(psum, goff, fc_w, fc_b, out);
}

// Round 19
// 341.831 us; speedup vs baseline: 1.0895x; 1.0418x over previous
//
#include <hip/hip_runtime.h>
#include <cstdint>
#include <cstddef>

#define Nn    4096
#define Ee    131072
#define INC   512
#define HIDC  512
#define HEADS 4
#define NLAY  3
#define GG    16
#define FW    2048   // HEADS*HIDC
#define ALDS  2112   // A LDS tile: 4 kq blocks x 66 rows x 8 shorts (bank-staggered)
#define BLDS  4160   // B LDS tile: 4 kq blocks x 130 rows x 8 shorts

typedef __attribute__((ext_vector_type(8))) short bfrag;   // 8 bf16 (4 VGPRs)
typedef __attribute__((ext_vector_type(4))) float ffrag;   // 4 fp32 acc

__device__ __forceinline__ ushort f2bf(float v){
  uint u = __builtin_bit_cast(uint, v);
  u += 0x7fffu + ((u>>16)&1u);          // RNE
  return (ushort)(u>>16);
}
__device__ __forceinline__ float bf2f(ushort s){
  uint u = ((uint)s)<<16; return __builtin_bit_cast(float, u);
}
// acc[0..7] += w * unpack8(bf16x8 in uint4)
__device__ __forceinline__ void fma8(float* acc, uint4 g, float w){
  uint u[4] = {g.x, g.y, g.z, g.w};
  #pragma unroll
  for (int q=0;q<4;q++){
    float lo = __builtin_bit_cast(float, u[q]<<16);
    float hi = __builtin_bit_cast(float, u[q] & 0xffff0000u);
    acc[2*q]   += w*lo;
    acc[2*q+1] += w*hi;
  }
}
__device__ __forceinline__ void pack8(void* p, const float* a){
  uint4 o;
  o.x = (uint)f2bf(a[0]) | ((uint)f2bf(a[1])<<16);
  o.y = (uint)f2bf(a[2]) | ((uint)f2bf(a[3])<<16);
  o.z = (uint)f2bf(a[4]) | ((uint)f2bf(a[5])<<16);
  o.w = (uint)f2bf(a[6]) | ((uint)f2bf(a[7])<<16);
  *(uint4*)p = o;
}
// pack 8 fp32 (two float4, memory order) -> 8 bf16 in uint4
__device__ __forceinline__ uint4 cvt8(float4 a, float4 b){
  uint4 o;
  o.x = (uint)f2bf(a.x) | ((uint)f2bf(a.y)<<16);
  o.y = (uint)f2bf(a.z) | ((uint)f2bf(a.w)<<16);
  o.z = (uint)f2bf(b.x) | ((uint)f2bf(b.y)<<16);
  o.w = (uint)f2bf(b.z) | ((uint)f2bf(b.w)<<16);
  return o;
}

// ---------------- fused prep: W transposes->bf16 | edge pass 1 ----------------
__global__ __launch_bounds__(256) void prep(
    const float* __restrict__ Wgat, ushort* __restrict__ Tgat,
    const float* __restrict__ Wgcn, ushort* __restrict__ Tgcn,
    const int* __restrict__ src, const int* __restrict__ dst,
    int* __restrict__ indeg, unsigned int* __restrict__ bitmap,
    int* __restrict__ cnt_s, int* __restrict__ flag){
  __shared__ float tile[32][33];
  int b = blockIdx.x, t = threadIdx.x;
  if (b < 1792){
    int z = b >> 8, xy = b & 255;
    const float* W; ushort* T; int bb;
    if (z < 4){ W = Wgat; T = Tgat; bb = z; } else { W = Wgcn; T = Tgcn; bb = z-4; }
    int r0 = (xy>>4)*32, c0 = (xy&15)*32;
    int i = t>>3, j0 = (t&7)*4;
    const float* Wb = W + (size_t)bb*512*512;
    float4 v = *(const float4*)(Wb + (size_t)(r0+i)*512 + c0 + j0);
    tile[i][j0]=v.x; tile[i][j0+1]=v.y; tile[i][j0+2]=v.z; tile[i][j0+3]=v.w;
    __syncthreads();
    ushort* o = T + (size_t)bb*512*512 + (size_t)(c0+i)*512 + r0 + j0;
    #pragma unroll
    for (int q=0;q<4;q++) o[q] = f2bf(tile[j0+q][i]);
  } else {
    int e = (b-1792)*256 + t; if (e>=Ee) return;
    int s = src[e], d = dst[e];
    atomicAdd(&indeg[d],1);
    unsigned int key = (unsigned int)s*Nn + (unsigned int)d;
    unsigned int bit = 1u<<(key&31);
    unsigned int old = atomicOr(&bitmap[key>>5], bit);
    int f = (old & bit) ? 0 : 1;
    flag[e] = f;
    if (f) atomicAdd(&cnt_s[s],1);
  }
}

// ---------------- bf16 MFMA GEMM core: C = A@B^T, 64(M)x128(N) tile, LDS double-buffer ----------------
// Bank-staggered LDS; AF32 = fp32 A operand (register f2bf); Res prefetched BEFORE K-loop.
template<bool AF32>
__device__ __forceinline__ void gemm_core(
    const void* __restrict__ Av, const ushort* __restrict__ B,
    const ushort* Res, ushort* Cb,
    int N, int K, int relu_res, int m0, int n0,
    ushort* Ah, ushort* Bh)
{
  int t = threadIdx.x;
  int srA = t>>2, kqA = t&3;
  int wA = (kqA*66 + srA)*8;
  int srB = t>>1, cB = t&1;
  const ushort* pB = B + (size_t)(n0+srB)*K + cB*16;
  int wB0 = ((2*cB)*130 + srB)*8;
  int wB1 = wB0 + 130*8;

  int wave = t>>6, lane = t&63;
  int wm = (wave&1)*32, wn = (wave>>1)*64;
  int lm = lane&15, quad = lane>>4;

  // ---- prefetch Res (epilogue operand) before the K-loop ----
  ushort resv[2][4][4];
  if (relu_res){
    #pragma unroll
    for (int mt=0; mt<2; mt++)
      #pragma unroll
      for (int r=0;r<4;r++){
        int grow = m0 + wm + mt*16 + quad*4 + r;
        #pragma unroll
        for (int nt=0; nt<4; nt++){
          int gcol = n0 + wn + nt*16 + lm;
          resv[mt][nt][r] = Res[(size_t)grow*N + gcol];
        }
      }
  }

  ffrag acc[2][4];
  #pragma unroll
  for (int i=0;i<2;i++){
    #pragma unroll
    for (int j=0;j<4;j++) acc[i][j] = (ffrag){0.f,0.f,0.f,0.f};
  }

  const ushort* pA16 = (const ushort*)Av + (size_t)(m0+srA)*K + kqA*8;
  const float*  pA32 = (const float*)Av  + (size_t)(m0+srA)*K + kqA*8;

  uint4 ra; float4 raf0, raf1;
  if (AF32){ raf0 = *(const float4*)(pA32); raf1 = *(const float4*)(pA32+4); }
  else     { ra = *(const uint4*)(pA16); }
  uint4 rb0 = *(const uint4*)(pB);  uint4 rb1 = *(const uint4*)(pB+8);
  *(uint4*)&Ah[wA]  = AF32 ? cvt8(raf0, raf1) : ra;
  *(uint4*)&Bh[wB0] = rb0; *(uint4*)&Bh[wB1] = rb1;
  if (K > 32){
    if (AF32){ raf0 = *(const float4*)(pA32+32); raf1 = *(const float4*)(pA32+36); }
    else     { ra = *(const uint4*)(pA16+32); }
    rb0 = *(const uint4*)(pB+32); rb1 = *(const uint4*)(pB+40);
  }
  __syncthreads();

  for (int k0 = 0; k0 < K; k0 += 32){
    int cur = (k0>>5)&1, nxt = cur^1;
    const ushort* Ac = Ah + cur*ALDS;
    const ushort* Bc = Bh + cur*BLDS;
    bfrag af[2];
    #pragma unroll
    for (int mt=0; mt<2; mt++)
      af[mt] = *(const bfrag*)&Ac[(quad*66 + wm + mt*16 + lm)*8];
    #pragma unroll
    for (int nt=0; nt<4; nt++){
      bfrag bf = *(const bfrag*)&Bc[(quad*130 + wn + nt*16 + lm)*8];
      #pragma unroll
      for (int mt=0; mt<2; mt++)
        acc[mt][nt] = __builtin_amdgcn_mfma_f32_16x16x32_bf16(af[mt], bf, acc[mt][nt], 0,0,0);
    }
    if (k0+32 < K){
      *(uint4*)&Ah[nxt*ALDS + wA]  = AF32 ? cvt8(raf0, raf1) : ra;
      *(uint4*)&Bh[nxt*BLDS + wB0] = rb0; *(uint4*)&Bh[nxt*BLDS + wB1] = rb1;
      if (k0+64 < K){
        if (AF32){ raf0 = *(const float4*)(pA32+k0+64); raf1 = *(const float4*)(pA32+k0+68); }
        else     { ra = *(const uint4*)(pA16+k0+64); }
        rb0 = *(const uint4*)(pB+k0+64); rb1 = *(const uint4*)(pB+k0+72);
      }
    }
    __syncthreads();
  }

  #pragma unroll
  for (int mt=0; mt<2; mt++){
    #pragma unroll
    for (int nt=0; nt<4; nt++){
      #pragma unroll
      for (int r=0;r<4;r++){
        int grow = m0 + wm + mt*16 + quad*4 + r;
        int gcol = n0 + wn + nt*16 + lm;
        size_t off = (size_t)grow*N + gcol;
        float v = acc[mt][nt][r];
        if (relu_res) v = fmaxf(v,0.f) + bf2f(resv[mt][nt][r]);
        Cb[off] = f2bf(v);
      }
    }
  }
}

__global__ __launch_bounds__(256) void gemm_bf(
    const ushort* __restrict__ A, const ushort* __restrict__ B,
    const ushort* Res, ushort* Cb,
    int N, int K, int relu_res)
{
  __shared__ __align__(16) ushort Ah[2*ALDS];
  __shared__ __align__(16) ushort Bh[2*BLDS];
  gemm_core<false>(A, B, Res, Cb, N, K, relu_res,
                   blockIdx.y*64, blockIdx.x*128, Ah, Bh);
}

// ---------------- fused: GAT projection gemm (fp32 A) + edge scatter ----------------
__global__ __launch_bounds__(256) void gat_gemm_ep2(
    const float* __restrict__ x, const ushort* __restrict__ WgatT, ushort* __restrict__ hbf,
    const int* __restrict__ src, const int* __restrict__ dst, const int* __restrict__ flag,
    const int* __restrict__ rp_d, int* __restrict__ fill_d, int* __restrict__ slist,
    const int* __restrict__ rp_s, int* __restrict__ fill_s, int2* __restrict__ cw,
    const float* __restrict__ dinv)
{
  __shared__ __align__(16) ushort Ah[2*ALDS];
  __shared__ __align__(16) ushort Bh[2*BLDS];
  int b = blockIdx.x;
  if (b < 1024){
    int m0 = (b>>4)*64, n0 = (b&15)*128;   // M=Nn (64 tiles), N=FW (16 tiles)
    gemm_core<true>(x, WgatT, nullptr, hbf, FW, INC, 0, m0, n0, Ah, Bh);
  } else {
    int e = (b-1024)*256 + threadIdx.x; if (e>=Ee) return;
    int s = src[e], d = dst[e];
    int p = atomicAdd(&fill_d[d],1); slist[rp_d[d]+p] = s;
    if (flag[e]){
      int q = atomicAdd(&fill_s[s],1);
      cw[rp_s[s]+q] = make_int2(d, __float_as_int(dinv[d]));
    }
  }
}

// ---------------- attention logits per (node,head) ----------------
__global__ __launch_bounds__(256) void compute_lg(const ushort* __restrict__ hbf,
    const float* __restrict__ a_src, const float* __restrict__ a_dst,
    float* __restrict__ lgs, float* __restrict__ lgd){
  int n = blockIdx.x; int t = threadIdx.x;
  int hd = t>>6, lane = t&63;
  uint4 g = *(const uint4*)(hbf + (size_t)n*FW + hd*HIDC + lane*8);
  float h[8] = {0,0,0,0,0,0,0,0};
  fma8(h, g, 1.0f);
  float4 as0 = *(const float4*)(a_src + hd*HIDC + lane*8);
  float4 as1 = *(const float4*)(a_src + hd*HIDC + lane*8 + 4);
  float4 ad0 = *(const float4*)(a_dst + hd*HIDC + lane*8);
  float4 ad1 = *(const float4*)(a_dst + hd*HIDC + lane*8 + 4);
  float s1 = h[0]*as0.x + h[1]*as0.y + h[2]*as0.z + h[3]*as0.w
           + h[4]*as1.x + h[5]*as1.y + h[6]*as1.z + h[7]*as1.w;
  float s2 = h[0]*ad0.x + h[1]*ad0.y + h[2]*ad0.z + h[3]*ad0.w
           + h[4]*ad1.x + h[5]*ad1.y + h[6]*ad1.z + h[7]*ad1.w;
  for (int off=32; off; off>>=1){ s1 += __shfl_down(s1,off); s2 += __shfl_down(s2,off); }
  if (lane==0){ lgs[n*HEADS+hd]=s1; lgd[n*HEADS+hd]=s2; }
}

// ---------------- scan3 ----------------
__global__ __launch_bounds__(1024) void scan3(const int* __restrict__ indeg, int* __restrict__ rp_d,
    const int* __restrict__ cnt_s, int* __restrict__ rp_s, float* __restrict__ dinv,
    const int* __restrict__ batch, int* __restrict__ goff){
  __shared__ int sums[1024];
  __shared__ int cnt2[GG];
  int t = threadIdx.x;
  if (blockIdx.x == 2){
    if (t<GG) cnt2[t]=0;
    __syncthreads();
    for (int i=t;i<Nn;i+=1024) atomicAdd(&cnt2[batch[i]],1);
    __syncthreads();
    if (t==0){ int run=0; for (int g=0; g<GG; g++){ goff[g]=run; run+=cnt2[g]; } goff[GG]=run; }
    return;
  }
  const int* cnt = blockIdx.x ? cnt_s : indeg;
  int* rowptr    = blockIdx.x ? rp_s  : rp_d;
  int v[4]; int s=0;
  #pragma unroll
  for (int i=0;i<4;i++){ int idx=t*4+i; v[i] = cnt[idx]; s+=v[i]; }
  sums[t]=s; __syncthreads();
  for (int off=1; off<1024; off<<=1){
    int other = (t>=off)? sums[t-off] : 0;
    __syncthreads();
    sums[t] += other;
    __syncthreads();
  }
  int run = (t>0)? sums[t-1] : 0;
  #pragma unroll
  for (int i=0;i<4;i++){
    int idx=t*4+i; rowptr[idx]=run; run+=v[i];
    if (blockIdx.x) dinv[idx] = 1.0f/sqrtf((float)(1+v[i]));
  }
  if (t==1023) rowptr[Nn]=sums[1023];
}

// ---------------- GAT softmax-aggregate: block = (4 nodes) x (1 head), wave = node ----------------
// Pass 3: alphas precomputed LANE-PARALLEL into per-wave LDS (256-edge chunks) — kills the
// 64x-redundant per-lane exp/lrelu/lgs-load; gather loop is ds_read(alpha) + uint4 gather + fma8,
// batch-4 depth-2 pipelined (r17-proven). Accumulation order & alpha values unchanged.
__global__ __launch_bounds__(256) void gat_aggregate(const ushort* __restrict__ hbf,
    const float* __restrict__ lgs, const float* __restrict__ lgd,
    const int* __restrict__ rowptr, const int* __restrict__ slist,
    ushort* __restrict__ Hbf){
  __shared__ float alds[4][256];
  int t = threadIdx.x;
  int wv = __builtin_amdgcn_readfirstlane(t>>6);
  int lane = t&63;
  int b = blockIdx.x;
  int hd = __builtin_amdgcn_readfirstlane(b & 3);
  int n = ((b>>2)<<2) + wv;
  int beg = __builtin_amdgcn_readfirstlane(rowptr[n]);
  int end = __builtin_amdgcn_readfirstlane(rowptr[n+1]);
  int deg = end - beg;
  float ldst = lgd[n*HEADS+hd];
  // ---- single-pass online softmax (m,z), lane-parallel ----
  float m_ = -3.4e38f, z_ = 0.f;
  for (int i=lane; i<deg; i+=64){
    int s = slist[beg+i];
    float v = lgs[s*HEADS+hd] + ldst;
    v = v>0.f ? v : 0.2f*v;
    float mn = fmaxf(m_, v);
    z_ = z_*__expf(m_-mn) + __expf(v-mn);
    m_ = mn;
  }
  for (int o=32;o;o>>=1){
    float mo = __shfl_down(m_,o), zo = __shfl_down(z_,o);
    float mn = fmaxf(m_, mo);
    z_ = z_*__expf(m_-mn) + zo*__expf(mo-mn);
    m_ = mn;
  }
  float mx = __shfl(m_,0);
  float zs = __shfl(z_,0);
  float inv = 1.f/(zs+1e-16f);
  // ---- weighted accumulate: 256-edge chunks; alpha precompute (lane-parallel) + pipelined gathers ----
  float acc[8] = {0,0,0,0,0,0,0,0};
  const ushort* hb = hbf + hd*HIDC + lane*8;
  float* aw = &alds[wv][0];
  for (int base = beg; base < end; base += 256){
    int cn = min(256, end-base);
    for (int i=lane; i<cn; i+=64){
      int s = slist[base+i];
      float v = lgs[s*HEADS+hd] + ldst;
      v = v>0.f ? v : 0.2f*v;
      aw[i] = __expf(v-mx)*inv;
    }
    // per-wave LDS region + in-order wave execution: no barrier needed
    int c = 0;
    if (c+4 <= cn){
      uint4 g0[4];
      #pragma unroll
      for (int q=0;q<4;q++) g0[q] = *(const uint4*)(hb + (size_t)slist[base+c+q]*FW);
      c += 4;
      for (; c+4<=cn; c+=4){
        uint4 g1[4];
        #pragma unroll
        for (int q=0;q<4;q++) g1[q] = *(const uint4*)(hb + (size_t)slist[base+c+q]*FW);
        #pragma unroll
        for (int q=0;q<4;q++) fma8(acc, g0[q], aw[c-4+q]);
        #pragma unroll
        for (int q=0;q<4;q++) g0[q]=g1[q];
      }
      #pragma unroll
      for (int q=0;q<4;q++) fma8(acc, g0[q], aw[c-4+q]);
    }
    for (; c<cn; c++){
      uint4 g = *(const uint4*)(hb + (size_t)slist[base+c]*FW);
      fma8(acc, g, aw[c]);
    }
  }
  size_t off = (size_t)n*FW + hd*HIDC + lane*8;
  pack8(Hbf + off, acc);
}

// ---------------- SpMM: scalar-uniform edge loop, pipelined depth-2 x batch-8 ----------------
__global__ __launch_bounds__(256) void spmm_bf(const ushort* __restrict__ Hbf,
    ushort* __restrict__ Phi,
    const int* __restrict__ rowptr, const int2* __restrict__ cw, const float* __restrict__ dinv){
  int t = threadIdx.x;
  int wv = __builtin_amdgcn_readfirstlane(t>>6);
  int lane = t&63;
  int b = blockIdx.x;
  int ck = __builtin_amdgcn_readfirstlane(b & 3);
  int n = ((b>>2)<<2) + wv;
  int f = (ck<<9) + lane*8;
  float di = dinv[n];
  float acc[8] = {0,0,0,0,0,0,0,0};
  const ushort* hb = Hbf + f;
  uint4 self = *(const uint4*)(hb + (size_t)n*FW);
  fma8(acc, self, di*di);
  int beg = __builtin_amdgcn_readfirstlane(rowptr[n]);
  int end = __builtin_amdgcn_readfirstlane(rowptr[n+1]);
  int i = beg;
  if (i+8 <= end){
    int2 e0[8]; uint4 g0[8];
    #pragma unroll
    for (int q=0;q<8;q++) e0[q] = cw[i+q];
    #pragma unroll
    for (int q=0;q<8;q++) g0[q] = *(const uint4*)(hb + (size_t)e0[q].x*FW);
    i += 8;
    for (; i+8<=end; i+=8){
      int2 e1[8]; uint4 g1[8];
      #pragma unroll
      for (int q=0;q<8;q++) e1[q] = cw[i+q];
      #pragma unroll
      for (int q=0;q<8;q++) g1[q] = *(const uint4*)(hb + (size_t)e1[q].x*FW);
      #pragma unroll
      for (int q=0;q<8;q++) fma8(acc, g0[q], di*__int_as_float(e0[q].y));
      #pragma unroll
      for (int q=0;q<8;q++){ e0[q]=e1[q]; g0[q]=g1[q]; }
    }
    #pragma unroll
    for (int q=0;q<8;q++) fma8(acc, g0[q], di*__int_as_float(e0[q].y));
  }
  for (; i<end; i++){
    int2 e = cw[i];
    uint4 g = *(const uint4*)(hb + (size_t)e.x*FW);
    fma8(acc, g, di*__int_as_float(e.y));
  }
  pack8(Phi + (size_t)n*FW + f, acc);
}

// ---------------- pooling ----------------
__global__ __launch_bounds__(256) void pool_accum(const ushort* __restrict__ Hb,
    const int* __restrict__ batch, float* __restrict__ psum){
  int d2 = blockIdx.y*256 + threadIdx.x;   // feature-pair index
  int n0 = blockIdx.x*32;
  int g = batch[n0];
  float s0 = 0.f, s1 = 0.f;
  for (int k=0;k<32;k++){
    int n = n0+k;
    int gn = batch[n];
    if (gn != g){
      atomicAdd(&psum[(size_t)g*FW + d2*2],   s0);
      atomicAdd(&psum[(size_t)g*FW + d2*2+1], s1);
      s0=0.f; s1=0.f; g=gn;
    }
    uint v = *(const uint*)(Hb + (size_t)n*FW + d2*2);
    s0 += bf2f((ushort)(v&0xffff));
    s1 += bf2f((ushort)(v>>16));
  }
  atomicAdd(&psum[(size_t)g*FW + d2*2],   s0);
  atomicAdd(&psum[(size_t)g*FW + d2*2+1], s1);
}
__global__ __launch_bounds__(256) void final_out(const float* __restrict__ psum,
    const int* __restrict__ goff,
    const float* __restrict__ fc_w, const float* __restrict__ fc_b, float* __restrict__ out){
  int g = blockIdx.x; int t = threadIdx.x;
  float cinv = 0.25f / fmaxf((float)(goff[g+1]-goff[g]), 1.f);
  float p = 0.f;
  for (int d=t; d<HIDC; d+=256){
    float f = cinv*(psum[(size_t)g*FW+d] + psum[(size_t)g*FW+HIDC+d]
                  + psum[(size_t)g*FW+2*HIDC+d] + psum[(size_t)g*FW+3*HIDC+d]);
    p += f*fc_w[d];
  }
  __shared__ float red[4];
  for (int off=32; off; off>>=1) p += __shfl_down(p,off);
  if ((t&63)==0) red[t>>6]=p;
  __syncthreads();
  if (t==0) out[g] = red[0]+red[1]+red[2]+red[3] + fc_b[0];
}

extern "C" void kernel_launch(void* const* d_in, const int* in_sizes, int n_in,
                              void* d_out, int out_size, void* d_ws, size_t ws_size,
                              hipStream_t stream){
  const float* x      = (const float*)d_in[0];
  const int*   ei     = (const int*)d_in[1];
  const int*   batch  = (const int*)d_in[2];
  const float* W_gat  = (const float*)d_in[3];
  const float* a_src  = (const float*)d_in[4];
  const float* a_dst  = (const float*)d_in[5];
  const float* W_gcn  = (const float*)d_in[6];
  const float* fc_w   = (const float*)d_in[7];
  const float* fc_b   = (const float*)d_in[8];
  float* out = (float*)d_out;
  const int* src = ei;
  const int* dst = ei + Ee;

  char* w = (char*)d_ws;
  size_t off = 0;
  auto alloc = [&](size_t bytes)->char*{ char* p = w + off; off = (off + bytes + 255) & ~(size_t)255; return p; };
  ushort* hbf    = (ushort*)alloc((size_t)Nn*FW*2);       // GAT projection; REUSED as Phi
  ushort* Hbf    = (ushort*)alloc((size_t)Nn*FW*2);       // bf16 node features H (residual trunk)
  ushort* WgatT  = (ushort*)alloc((size_t)HEADS*INC*HIDC*2);
  ushort* WgcnT  = (ushort*)alloc((size_t)NLAY*HIDC*HIDC*2);
  float* lgs    = (float*)alloc((size_t)Nn*HEADS*4);
  float* lgd    = (float*)alloc((size_t)Nn*HEADS*4);
  // ---- contiguous zero-init region (single memset) ----
  int* indeg    = (int*)alloc(Nn*4);
  int* fill_d   = (int*)alloc(Nn*4);
  int* cnt_s    = (int*)alloc(Nn*4);
  int* fill_s   = (int*)alloc(Nn*4);
  float* psum   = (float*)alloc((size_t)GG*FW*4);
  unsigned int* bitmap = (unsigned int*)alloc((size_t)Nn*Nn/8);
  size_t zero_bytes = (size_t)Nn*4*4 + (size_t)GG*FW*4 + (size_t)Nn*Nn/8;
  // ---- rest ----
  int* rowptr_d = (int*)alloc((Nn+1)*4);
  int* slist    = (int*)alloc(Ee*4);
  int* rowptr_s = (int*)alloc((Nn+1)*4);
  int2* cwlist  = (int2*)alloc((size_t)Ee*8);
  int* flag     = (int*)alloc(Ee*4);
  float* dinv   = (float*)alloc(Nn*4);
  int* goff     = (int*)alloc((GG+1)*4);
  ushort* Phi   = hbf;

  hipMemsetAsync(indeg, 0, zero_bytes, stream);

  // ---- fused prep (W transposes + edge pass 1) ----
  prep<<<2304,256,0,stream>>>(W_gat, WgatT, W_gcn, WgcnT,
                              src, dst, indeg, bitmap, cnt_s, flag);

  // ---- CSR scans ----
  scan3<<<3,1024,0,stream>>>(indeg, rowptr_d, cnt_s, rowptr_s, dinv, batch, goff);

  // ---- GAT projection gemm (fp32 A) + edge scatter, fused ----
  gat_gemm_ep2<<<1536,256,0,stream>>>(x, WgatT, hbf,
      src, dst, flag, rowptr_d, fill_d, slist, rowptr_s, fill_s, cwlist, dinv);

  compute_lg<<<Nn,256,0,stream>>>(hbf, a_src, a_dst, lgs, lgd);
  gat_aggregate<<<Nn,256,0,stream>>>(hbf, lgs, lgd, rowptr_d, slist, Hbf);

  // ---- residual GCN layers (bf16 trunk) ----
  for (int l=0;l<NLAY;l++){
    spmm_bf<<<Nn,256,0,stream>>>(Hbf, Phi, rowptr_s, cwlist, dinv);
    gemm_bf<<<dim3(HIDC/128, (Nn*HEADS)/64),256,0,stream>>>(Phi,
        WgcnT + (size_t)l*HIDC*HIDC,
        Hbf, Hbf, HIDC, HIDC, 1);
  }

  // ---- pooling + FC ----
  pool_accum<<<dim3(Nn/32, FW/512),256,0,stream>>>(Hbf, batch, psum);
  final_out<<<GG,256,0,stream>>>(psum, goff, fc_w, fc_b, out);
}